// Round 1
// baseline (1589.206 us; speedup 1.0000x reference)
//
#include <hip/hip_runtime.h>

// LOBRM fused recurrence on gfx950 — fp16 hi/lo split-precision MFMA, R9.
// R9 = R8 pipeline with M=8 row tile / grid=512 -> 2 independent blocks per CU.
// R8 counters showed 1 wave/SIMD (Occupancy 11.7%), MfmaUtil 12%, VALU 45%,
// HBM 1% => latency-bound serial chain with zero cross-work to hide it.
// Rows are independent in every matmul, so halving rows/block and doubling the
// grid gives exactly 2 resident blocks/CU (LDS 89KB<160KB, VGPR 204<=256):
// each block's barrier drains + LDS/MFMA latency fill with the other block's
// issue. MFMA count doubles (half-garbage M tile) — cheap at 12% util.
// Garbage rows 8..15: row-independent, tanh-bounded (no overflow), never get
// feat (masks zero, sFlg zero-init), never stored (epilogue predicated).
//  - feat global loads prefetched ONE STEP AHEAD (2 rows/wave now)
//  - MFMA hh-chains init with bias splat
//  - __ballot flag (msk half of data is abs()'d: sum>0 <=> any>0)
//  - vol = hh term only (leaf output, error ~0.03 << 0.705)
//  - sT aliased for Hn (disjoint lifetimes)

typedef __attribute__((ext_vector_type(8))) _Float16 half8;  // 8 fp16 = 4 VGPRs
typedef __attribute__((ext_vector_type(4))) float floatx4;   // MFMA C/D

#define MFMA(a, b, c) __builtin_amdgcn_mfma_f32_16x16x32_f16((a), (b), (c), 0, 0, 0)

__device__ __forceinline__ float tanhf_fast(float x) {
    float e = __builtin_exp2f(x * 2.8853900817779268f);  // e^{2x}
    return 1.0f - 2.0f / (e + 1.0f);                     // inf-safe: ->1 / -1
}
__device__ __forceinline__ float sigmoidf_fast(float x) {
    float e = __builtin_exp2f(x * -1.4426950408889634f); // e^{-x}
    return 1.0f / (1.0f + e);
}

struct W2 { half8 h, l; };

__global__ __launch_bounds__(256, 2)
void lobrm_fused(const float* __restrict__ data,   // (4096,64,100)
                 const int*   __restrict__ tsteps, // (4096,64)
                 const float* __restrict__ Wu1, const float* __restrict__ bu1,
                 const float* __restrict__ Wu2, const float* __restrict__ bu2,
                 const float* __restrict__ Wr1, const float* __restrict__ br1,
                 const float* __restrict__ Wr2, const float* __restrict__ br2,
                 const float* __restrict__ Wn1, const float* __restrict__ bn1,
                 const float* __restrict__ Wn2, const float* __restrict__ bn2,
                 const float* __restrict__ Wo1, const float* __restrict__ bo1,
                 const float* __restrict__ Wo2, const float* __restrict__ bo2,
                 const float* __restrict__ Wd,  const float* __restrict__ bd,
                 float* __restrict__ out)
{
    // fp16 hi/lo activation buffers. Row strides 72/136 halfs: 16B-aligned.
    // sTh/sTl double as Hn buffers (T: mm1->mm2, Hn: mm5->mm6; disjoint).
    // Buffers stay 16 rows tall (A-frag reads row=col16 in 0..15); rows 8..15
    // carry a bounded garbage recurrence that only feeds discarded outputs.
    __shared__ __align__(16) _Float16 sYh [16 * 72],  sYl [16 * 72];
    __shared__ __align__(16) _Float16 sTh [16 * 72],  sTl [16 * 72];
    __shared__ __align__(16) _Float16 sHuh[16 * 72],  sHul[16 * 72];
    __shared__ __align__(16) _Float16 sHrh[16 * 72],  sHrl[16 * 72];
    __shared__ __align__(16) _Float16 sYCh[16 * 136], sYCl[16 * 136]; // [y1|feat|0]
    __shared__ __align__(16) _Float16 sCCh[16 * 136], sCCl[16 * 136]; // [y1*r|feat|0]
    __shared__ float    sVol[16 * 132];   // vol per row per step
    __shared__ unsigned sFlg[16];         // apply = upd && m, per row

    const int tid   = threadIdx.x;
    const int lane  = tid & 63;
    const int wv    = tid >> 6;          // wave = N-slice
    const int col16 = lane & 15;
    const int quad  = lane >> 4;
    const int ncol  = wv * 16 + col16;   // output column 0..63
    const int rowBase = blockIdx.x * 8;  // M=8: 512 blocks, 2 per CU

    // ---- prologue: zero state + pad regions (pads must stay 0 forever) ----
    for (int x = tid; x < 16 * 72; x += 256) {
        sYh[x] = (_Float16)0.f; sYl[x] = (_Float16)0.f;
    }
    for (int x = tid; x < 16 * 136; x += 256) {
        sYCh[x] = (_Float16)0.f; sYCl[x] = (_Float16)0.f;
        sCCh[x] = (_Float16)0.f; sCCl[x] = (_Float16)0.f;
    }
    if (tid < 16) sFlg[tid] = 0u;        // rows 8..15 stay 0 forever
    const float bdv = bd[0];

    // ---- weight hi/lo B-fragments (this wave's 16-col slice) ----
    // B-frag for 16x16x32: lane holds B[k = kb*32 + quad*8 + j][n = ncol]
    auto loadW = [&](const float* W, int Kw, int kb) -> W2 {
        W2 f;
#pragma unroll
        for (int j = 0; j < 8; ++j) {
            int k = kb * 32 + quad * 8 + j;
            float v = (k < Kw) ? W[k * 64 + ncol] : 0.0f;
            _Float16 h = (_Float16)v;
            f.h[j] = h;
            f.l[j] = (_Float16)(v - (float)h);
        }
        return f;
    };
    W2 wO1[2], wO2[2], wU2[2], wR2[2], wN2[2], wU1[4], wR1[4], wN1[4];
#pragma unroll
    for (int kb = 0; kb < 2; ++kb) {
        wO1[kb] = loadW(Wo1, 64, kb);
        wO2[kb] = loadW(Wo2, 64, kb);
        wU2[kb] = loadW(Wu2, 64, kb);
        wR2[kb] = loadW(Wr2, 64, kb);
        wN2[kb] = loadW(Wn2, 64, kb);
    }
#pragma unroll
    for (int kb = 0; kb < 4; ++kb) {
        wU1[kb] = loadW(Wu1, 114, kb);
        wR1[kb] = loadW(Wr1, 114, kb);
        wN1[kb] = loadW(Wn1, 114, kb);
    }
    // vol B-frag (only wave 0 uses it): column 0 = Wd, cols 1..15 = 0.
    // hi-only: vol is a leaf output, lo terms contribute ~0.03 abs.
    half8 vwd[2];
#pragma unroll
    for (int kb = 0; kb < 2; ++kb)
#pragma unroll
        for (int j = 0; j < 8; ++j) {
            int k = kb * 32 + quad * 8 + j;
            vwd[kb][j] = (_Float16)((col16 == 0) ? Wd[k] : 0.0f);
        }
    const float bo1v = bo1[ncol], bo2v = bo2[ncol];
    const float bu1v = bu1[ncol], bu2v = bu2[ncol];
    const float br1v = br1[ncol], br2v = br2[ncol];
    const float bn1v = bn1[ncol], bn2v = bn2[ncol];

    // ---- presence masks (dedup == reference's presence): wave wv owns
    // rows 2wv..2wv+1 for feat loading ----
    unsigned long long mLo[2], mHi[2];
    const float* dPtr[2];
#pragma unroll
    for (int r4 = 0; r4 < 2; ++r4) {
        int b = rowBase + 2 * wv + r4;
        int v = tsteps[b * 64 + lane];
        unsigned long long lo = (v < 64) ? (1ull << v) : 0ull;
        unsigned long long hi = (v >= 64) ? (1ull << (v - 64)) : 0ull;
#pragma unroll
        for (int st = 1; st < 64; st <<= 1) {
            lo |= __shfl_xor(lo, st);
            hi |= __shfl_xor(hi, st);
        }
        mLo[r4] = lo; mHi[r4] = hi;
        dPtr[r4] = data + (size_t)b * 6400;
    }
    __syncthreads();

    floatx4 pc = {0.f, 0.f, 0.f, 0.f};   // fp32 state, C-layout slice
    const floatx4 z = {0.f, 0.f, 0.f, 0.f};

    const int aOff  = col16 * 72 + quad * 8;   // stride-72 A-frag base
    const int aOffH = col16 * 136 + quad * 8;  // stride-136 A-frag base

    // ---- prefetch step 0's feat loads ----
    bool hasU[2];
    float fv[2], mv[2];
#pragma unroll
    for (int r4 = 0; r4 < 2; ++r4) {
        hasU[r4] = (mLo[r4] & 1ull) != 0ull;
        fv[r4] = 0.f; mv[r4] = 0.f;
        if (hasU[r4]) {
            const float* dp = dPtr[r4];
            dPtr[r4] = dp + 100;
            if (lane < 50) { fv[r4] = dp[lane]; mv[r4] = dp[50 + lane]; }
        }
    }

    for (int i = 0; i < 128; ++i) {
        // ---- A) issue NEXT step's feat loads (consumed next iteration;
        //      the vmcnt(0) drain at B1 gives them the mm1 segment to land) ----
        const int ip = i + 1;
        bool hasN[2];
        float fN[2], mN[2];
#pragma unroll
        for (int r4 = 0; r4 < 2; ++r4) {
            unsigned long long mm =
                (ip < 64) ? (mLo[r4] >> ip)
                          : ((ip < 128) ? (mHi[r4] >> (ip - 64)) : 0ull);
            hasN[r4] = (mm & 1ull) != 0ull;
            fN[r4] = 0.f; mN[r4] = 0.f;
            if (hasN[r4]) {
                const float* dp = dPtr[r4];
                dPtr[r4] = dp + 100;
                if (lane < 50) { fN[r4] = dp[lane]; mN[r4] = dp[50 + lane]; }
            }
        }

        // ---- mm1: t = tanh(y @ Wo1 + bo1); wave 0: vol = y @ Wd + bd ----
        {
            half8 a0h = *(const half8*)&sYh[aOff];
            half8 a0l = *(const half8*)&sYl[aOff];
            half8 a1h = *(const half8*)&sYh[aOff + 32];
            half8 a1l = *(const half8*)&sYl[aOff + 32];
            floatx4 cb = {bo1v, bo1v, bo1v, bo1v};
            floatx4 hh = MFMA(a1h, wO1[1].h, MFMA(a0h, wO1[0].h, cb));
            floatx4 hl = MFMA(a1h, wO1[1].l, MFMA(a0h, wO1[0].l, z));
            floatx4 lh = MFMA(a1l, wO1[1].h, MFMA(a0l, wO1[0].h, z));
            if (wv == 0) {
                floatx4 v = MFMA(a1h, vwd[1], MFMA(a0h, vwd[0], z));
                if (col16 == 0) {
#pragma unroll
                    for (int r = 0; r < 4; ++r)
                        sVol[(quad * 4 + r) * 132 + i] = v[r] + bdv;
                }
            }
            floatx4 acc = hh + (hl + lh);
#pragma unroll
            for (int r = 0; r < 4; ++r) {
                float t = tanhf_fast(acc[r]);
                _Float16 h = (_Float16)t;
                int idx = (quad * 4 + r) * 72 + ncol;
                sTh[idx] = h;
                sTl[idx] = (_Float16)(t - (float)h);
            }
        }
        __syncthreads();                                   // B1

        // ---- mm2: y1 = y + t @ Wo2 + bo2 ----
        floatx4 y1;
        {
            half8 t0h = *(const half8*)&sTh[aOff];
            half8 t0l = *(const half8*)&sTl[aOff];
            half8 t1h = *(const half8*)&sTh[aOff + 32];
            half8 t1l = *(const half8*)&sTl[aOff + 32];
            floatx4 cb = {bo2v, bo2v, bo2v, bo2v};
            floatx4 hh = MFMA(t1h, wO2[1].h, MFMA(t0h, wO2[0].h, cb));
            floatx4 hl = MFMA(t1h, wO2[1].l, MFMA(t0h, wO2[0].l, z));
            floatx4 lh = MFMA(t1l, wO2[1].h, MFMA(t0l, wO2[0].h, z));
            floatx4 acc = hh + (hl + lh);
#pragma unroll
            for (int r = 0; r < 4; ++r) {
                y1[r] = pc[r] + acc[r];
                _Float16 h = (_Float16)y1[r];
                int idx = (quad * 4 + r) * 136 + ncol;
                sYCh[idx] = h;
                sYCl[idx] = (_Float16)(y1[r] - (float)h);
            }
        }

        // ---- C) feat commit (hi+lo, prefetched last iter) + ballot flags ----
#pragma unroll
        for (int r4 = 0; r4 < 2; ++r4) {
            int row = 2 * wv + r4;
            if (hasU[r4]) {
                if (lane < 50) {
                    float f = fv[r4];
                    _Float16 h = (_Float16)f;
                    _Float16 l = (_Float16)(f - (float)h);
                    int idx = row * 136 + 64 + lane;
                    sYCh[idx] = h; sYCl[idx] = l;
                    sCCh[idx] = h; sCCl[idx] = l;
                }
                unsigned long long bal = __ballot(mv[r4] > 0.f);
                if (lane == 0) sFlg[row] = bal ? 1u : 0u;
            } else if (lane == 0) {
                sFlg[row] = 0u;
            }
        }
        __syncthreads();                                   // B2

        // ---- mm3: hu = tanh(yc@Wu1+bu1), hr = tanh(yc@Wr1+br1), K=128 ----
        {
            half8 ah0 = *(const half8*)&sYCh[aOffH];
            half8 ah1 = *(const half8*)&sYCh[aOffH + 32];
            half8 ah2 = *(const half8*)&sYCh[aOffH + 64];
            half8 ah3 = *(const half8*)&sYCh[aOffH + 96];
            half8 al0 = *(const half8*)&sYCl[aOffH];
            half8 al1 = *(const half8*)&sYCl[aOffH + 32];
            half8 al2 = *(const half8*)&sYCl[aOffH + 64];
            half8 al3 = *(const half8*)&sYCl[aOffH + 96];
            floatx4 cu = {bu1v, bu1v, bu1v, bu1v};
            floatx4 cr = {br1v, br1v, br1v, br1v};
            floatx4 uhh = MFMA(ah3, wU1[3].h, MFMA(ah2, wU1[2].h,
                          MFMA(ah1, wU1[1].h, MFMA(ah0, wU1[0].h, cu))));
            floatx4 uhl = MFMA(ah3, wU1[3].l, MFMA(ah2, wU1[2].l,
                          MFMA(ah1, wU1[1].l, MFMA(ah0, wU1[0].l, z))));
            floatx4 ulh = MFMA(al3, wU1[3].h, MFMA(al2, wU1[2].h,
                          MFMA(al1, wU1[1].h, MFMA(al0, wU1[0].h, z))));
            floatx4 rhh = MFMA(ah3, wR1[3].h, MFMA(ah2, wR1[2].h,
                          MFMA(ah1, wR1[1].h, MFMA(ah0, wR1[0].h, cr))));
            floatx4 rhl = MFMA(ah3, wR1[3].l, MFMA(ah2, wR1[2].l,
                          MFMA(ah1, wR1[1].l, MFMA(ah0, wR1[0].l, z))));
            floatx4 rlh = MFMA(al3, wR1[3].h, MFMA(al2, wR1[2].h,
                          MFMA(al1, wR1[1].h, MFMA(al0, wR1[0].h, z))));
            floatx4 aU = uhh + (uhl + ulh);
            floatx4 aR = rhh + (rhl + rlh);
#pragma unroll
            for (int r = 0; r < 4; ++r) {
                float tu = tanhf_fast(aU[r]);
                float tr = tanhf_fast(aR[r]);
                int idx = (quad * 4 + r) * 72 + ncol;
                _Float16 hu = (_Float16)tu, hr = (_Float16)tr;
                sHuh[idx] = hu; sHul[idx] = (_Float16)(tu - (float)hu);
                sHrh[idx] = hr; sHrl[idx] = (_Float16)(tr - (float)hr);
            }
        }
        __syncthreads();                                   // B3

        // ---- mm4: u = sig(hu@Wu2+bu2), r = sig(hr@Wr2+br2); cc = y1*r ----
        floatx4 uG;
        {
            half8 u0h = *(const half8*)&sHuh[aOff];
            half8 u0l = *(const half8*)&sHul[aOff];
            half8 u1h = *(const half8*)&sHuh[aOff + 32];
            half8 u1l = *(const half8*)&sHul[aOff + 32];
            floatx4 cu = {bu2v, bu2v, bu2v, bu2v};
            floatx4 cr = {br2v, br2v, br2v, br2v};
            floatx4 au = MFMA(u1h, wU2[1].h, MFMA(u0h, wU2[0].h, cu))
                       + (MFMA(u1h, wU2[1].l, MFMA(u0h, wU2[0].l, z))
                        + MFMA(u1l, wU2[1].h, MFMA(u0l, wU2[0].h, z)));
            half8 r0h = *(const half8*)&sHrh[aOff];
            half8 r0l = *(const half8*)&sHrl[aOff];
            half8 r1h = *(const half8*)&sHrh[aOff + 32];
            half8 r1l = *(const half8*)&sHrl[aOff + 32];
            floatx4 ar = MFMA(r1h, wR2[1].h, MFMA(r0h, wR2[0].h, cr))
                       + (MFMA(r1h, wR2[1].l, MFMA(r0h, wR2[0].l, z))
                        + MFMA(r1l, wR2[1].h, MFMA(r0l, wR2[0].h, z)));
#pragma unroll
            for (int r = 0; r < 4; ++r) {
                uG[r] = sigmoidf_fast(au[r]);
                float rg = sigmoidf_fast(ar[r]);
                float cc = y1[r] * rg;
                _Float16 h = (_Float16)cc;
                int idx = (quad * 4 + r) * 136 + ncol;
                sCCh[idx] = h;
                sCCl[idx] = (_Float16)(cc - (float)h);
            }
        }
        __syncthreads();                                   // B4

        // ---- mm5: hn = tanh(cc @ Wn1 + bn1), K=128 (into sT alias) ----
        {
            half8 ah0 = *(const half8*)&sCCh[aOffH];
            half8 ah1 = *(const half8*)&sCCh[aOffH + 32];
            half8 ah2 = *(const half8*)&sCCh[aOffH + 64];
            half8 ah3 = *(const half8*)&sCCh[aOffH + 96];
            half8 al0 = *(const half8*)&sCCl[aOffH];
            half8 al1 = *(const half8*)&sCCl[aOffH + 32];
            half8 al2 = *(const half8*)&sCCl[aOffH + 64];
            half8 al3 = *(const half8*)&sCCl[aOffH + 96];
            floatx4 cn = {bn1v, bn1v, bn1v, bn1v};
            floatx4 nhh = MFMA(ah3, wN1[3].h, MFMA(ah2, wN1[2].h,
                          MFMA(ah1, wN1[1].h, MFMA(ah0, wN1[0].h, cn))));
            floatx4 nhl = MFMA(ah3, wN1[3].l, MFMA(ah2, wN1[2].l,
                          MFMA(ah1, wN1[1].l, MFMA(ah0, wN1[0].l, z))));
            floatx4 nlh = MFMA(al3, wN1[3].h, MFMA(al2, wN1[2].h,
                          MFMA(al1, wN1[1].h, MFMA(al0, wN1[0].h, z))));
            floatx4 aN = nhh + (nhl + nlh);
#pragma unroll
            for (int r = 0; r < 4; ++r) {
                float t = tanhf_fast(aN[r]);
                _Float16 h = (_Float16)t;
                int idx = (quad * 4 + r) * 72 + ncol;
                sTh[idx] = h;
                sTl[idx] = (_Float16)(t - (float)h);
            }
        }
        __syncthreads();                                   // B5

        // ---- mm6: ns = hn@Wn2 + bn2; blend; state update ----
        {
            half8 n0h = *(const half8*)&sTh[aOff];
            half8 n0l = *(const half8*)&sTl[aOff];
            half8 n1h = *(const half8*)&sTh[aOff + 32];
            half8 n1l = *(const half8*)&sTl[aOff + 32];
            floatx4 cn = {bn2v, bn2v, bn2v, bn2v};
            floatx4 acc = MFMA(n1h, wN2[1].h, MFMA(n0h, wN2[0].h, cn))
                        + (MFMA(n1h, wN2[1].l, MFMA(n0h, wN2[0].l, z))
                         + MFMA(n1l, wN2[1].h, MFMA(n0l, wN2[0].h, z)));
#pragma unroll
            for (int r = 0; r < 4; ++r) {
                float ns = acc[r];
                float ny = (1.0f - uG[r]) * ns + uG[r] * y1[r];
                unsigned ap = sFlg[quad * 4 + r];          // upd && m
                float nY = ap ? ny : y1[r];                // select: NaN-safe
                pc[r] = nY;
                int rr = quad * 4 + r;
                _Float16 h = (_Float16)nY;
                sYh[rr * 72 + ncol] = h;
                sYl[rr * 72 + ncol] = (_Float16)(nY - (float)h);
            }
        }
        __syncthreads();                                   // B6

        // ---- rotate prefetched feat ----
#pragma unroll
        for (int r4 = 0; r4 < 2; ++r4) {
            hasU[r4] = hasN[r4];
            fv[r4] = fN[r4];
            mv[r4] = mN[r4];
        }
    }

    // ---- epilogue (only real rows 0..7 stored) ----
    if (quad < 2) {
#pragma unroll
        for (int r = 0; r < 4; ++r) {
            int b = rowBase + quad * 4 + r;
            out[(size_t)b * 64 + ncol] = pc[r];
        }
    }
    float* out1 = out + (size_t)4096 * 64;
    float* out2 = out1 + (size_t)4096 * 63;
#pragma unroll
    for (int r4 = 0; r4 < 2; ++r4) {
        int row = 2 * wv + r4;
        int b = rowBase + row;
        if (lane < 63) {
            int t0 = tsteps[b * 64 + lane];
            int t1 = tsteps[b * 64 + lane + 1];
            int iv = t0 < 126 ? t0 : 126;
            out1[(size_t)b * 63 + lane] = sVol[row * 132 + iv + 1];
            out2[(size_t)b * 63 + lane] = (float)(t1 - t0);
        }
    }
}

extern "C" void kernel_launch(void* const* d_in, const int* in_sizes, int n_in,
                              void* d_out, int out_size, void* d_ws, size_t ws_size,
                              hipStream_t stream) {
    const float* data   = (const float*)d_in[0];
    const int*   tsteps = (const int*)  d_in[1];
    const float* Wu1 = (const float*)d_in[2];  const float* bu1 = (const float*)d_in[3];
    const float* Wu2 = (const float*)d_in[4];  const float* bu2 = (const float*)d_in[5];
    const float* Wr1 = (const float*)d_in[6];  const float* br1 = (const float*)d_in[7];
    const float* Wr2 = (const float*)d_in[8];  const float* br2 = (const float*)d_in[9];
    const float* Wn1 = (const float*)d_in[10]; const float* bn1 = (const float*)d_in[11];
    const float* Wn2 = (const float*)d_in[12]; const float* bn2 = (const float*)d_in[13];
    const float* Wo1 = (const float*)d_in[14]; const float* bo1 = (const float*)d_in[15];
    const float* Wo2 = (const float*)d_in[16]; const float* bo2 = (const float*)d_in[17];
    const float* Wd  = (const float*)d_in[18]; const float* bd  = (const float*)d_in[19];
    float* out = (float*)d_out;

    lobrm_fused<<<dim3(512), dim3(256), 0, stream>>>(
        data, tsteps, Wu1, bu1, Wu2, bu2, Wr1, br1, Wr2, br2,
        Wn1, bn1, Wn2, bn2, Wo1, bo1, Wo2, bo2, Wd, bd, out);
}

// Round 2
// 1001.464 us; speedup vs baseline: 1.5869x; 1.5869x over previous
//
#include <hip/hip_runtime.h>

// LOBRM fused recurrence on gfx950 — fp16 hi/lo split-precision MFMA, R10.
// R10 = R9 (M=8 tile, grid=512, 2 blocks/CU) with __launch_bounds__(256,1).
// R9 post-mortem: launch_bounds(256,2) FORCED VGPR to 128 < the ~176 needed
// for pinned weight fragments -> per-iteration scratch spills (FETCH_SIZE
// 42MB -> 2.4GB, dur 488 -> 1480us). The occupancy thesis needs no coercion:
// VGPR=204 <= 256 already permits 2 waves/SIMD at runtime (occupancy steps at
// 64/128/256); launch_bounds' 2nd arg is only a regalloc floor. So keep the
// R8 register budget (204, no spill) and let 2 blocks/CU co-reside naturally:
// LDS 2x43.5KB=87KB<160KB, grid 512 = exactly 2 resident per CU.
// Each block's barrier drains + LDS/MFMA latency fill with the other block's
// issue. MFMA count doubles (half-garbage M tile) — cheap at 12% util.
// Garbage rows 8..15: row-independent, tanh-bounded (no overflow), never get
// feat (masks zero, sFlg zero-init), never stored (epilogue predicated).
//  - feat global loads prefetched ONE STEP AHEAD (2 rows/wave)
//  - MFMA hh-chains init with bias splat
//  - __ballot flag (msk half of data is abs()'d: sum>0 <=> any>0)
//  - vol = hh term only (leaf output, error ~0.03 << 0.705)
//  - sT aliased for Hn (disjoint lifetimes)

typedef __attribute__((ext_vector_type(8))) _Float16 half8;  // 8 fp16 = 4 VGPRs
typedef __attribute__((ext_vector_type(4))) float floatx4;   // MFMA C/D

#define MFMA(a, b, c) __builtin_amdgcn_mfma_f32_16x16x32_f16((a), (b), (c), 0, 0, 0)

__device__ __forceinline__ float tanhf_fast(float x) {
    float e = __builtin_exp2f(x * 2.8853900817779268f);  // e^{2x}
    return 1.0f - 2.0f / (e + 1.0f);                     // inf-safe: ->1 / -1
}
__device__ __forceinline__ float sigmoidf_fast(float x) {
    float e = __builtin_exp2f(x * -1.4426950408889634f); // e^{-x}
    return 1.0f / (1.0f + e);
}

struct W2 { half8 h, l; };

__global__ __launch_bounds__(256, 1)
void lobrm_fused(const float* __restrict__ data,   // (4096,64,100)
                 const int*   __restrict__ tsteps, // (4096,64)
                 const float* __restrict__ Wu1, const float* __restrict__ bu1,
                 const float* __restrict__ Wu2, const float* __restrict__ bu2,
                 const float* __restrict__ Wr1, const float* __restrict__ br1,
                 const float* __restrict__ Wr2, const float* __restrict__ br2,
                 const float* __restrict__ Wn1, const float* __restrict__ bn1,
                 const float* __restrict__ Wn2, const float* __restrict__ bn2,
                 const float* __restrict__ Wo1, const float* __restrict__ bo1,
                 const float* __restrict__ Wo2, const float* __restrict__ bo2,
                 const float* __restrict__ Wd,  const float* __restrict__ bd,
                 float* __restrict__ out)
{
    // fp16 hi/lo activation buffers. Row strides 72/136 halfs: 16B-aligned.
    // sTh/sTl double as Hn buffers (T: mm1->mm2, Hn: mm5->mm6; disjoint).
    // Buffers stay 16 rows tall (A-frag reads row=col16 in 0..15); rows 8..15
    // carry a bounded garbage recurrence that only feeds discarded outputs.
    __shared__ __align__(16) _Float16 sYh [16 * 72],  sYl [16 * 72];
    __shared__ __align__(16) _Float16 sTh [16 * 72],  sTl [16 * 72];
    __shared__ __align__(16) _Float16 sHuh[16 * 72],  sHul[16 * 72];
    __shared__ __align__(16) _Float16 sHrh[16 * 72],  sHrl[16 * 72];
    __shared__ __align__(16) _Float16 sYCh[16 * 136], sYCl[16 * 136]; // [y1|feat|0]
    __shared__ __align__(16) _Float16 sCCh[16 * 136], sCCl[16 * 136]; // [y1*r|feat|0]
    __shared__ float    sVol[16 * 132];   // vol per row per step
    __shared__ unsigned sFlg[16];         // apply = upd && m, per row

    const int tid   = threadIdx.x;
    const int lane  = tid & 63;
    const int wv    = tid >> 6;          // wave = N-slice
    const int col16 = lane & 15;
    const int quad  = lane >> 4;
    const int ncol  = wv * 16 + col16;   // output column 0..63
    const int rowBase = blockIdx.x * 8;  // M=8: 512 blocks, 2 per CU

    // ---- prologue: zero state + pad regions (pads must stay 0 forever) ----
    for (int x = tid; x < 16 * 72; x += 256) {
        sYh[x] = (_Float16)0.f; sYl[x] = (_Float16)0.f;
    }
    for (int x = tid; x < 16 * 136; x += 256) {
        sYCh[x] = (_Float16)0.f; sYCl[x] = (_Float16)0.f;
        sCCh[x] = (_Float16)0.f; sCCl[x] = (_Float16)0.f;
    }
    if (tid < 16) sFlg[tid] = 0u;        // rows 8..15 stay 0 forever
    const float bdv = bd[0];

    // ---- weight hi/lo B-fragments (this wave's 16-col slice) ----
    // B-frag for 16x16x32: lane holds B[k = kb*32 + quad*8 + j][n = ncol]
    auto loadW = [&](const float* W, int Kw, int kb) -> W2 {
        W2 f;
#pragma unroll
        for (int j = 0; j < 8; ++j) {
            int k = kb * 32 + quad * 8 + j;
            float v = (k < Kw) ? W[k * 64 + ncol] : 0.0f;
            _Float16 h = (_Float16)v;
            f.h[j] = h;
            f.l[j] = (_Float16)(v - (float)h);
        }
        return f;
    };
    W2 wO1[2], wO2[2], wU2[2], wR2[2], wN2[2], wU1[4], wR1[4], wN1[4];
#pragma unroll
    for (int kb = 0; kb < 2; ++kb) {
        wO1[kb] = loadW(Wo1, 64, kb);
        wO2[kb] = loadW(Wo2, 64, kb);
        wU2[kb] = loadW(Wu2, 64, kb);
        wR2[kb] = loadW(Wr2, 64, kb);
        wN2[kb] = loadW(Wn2, 64, kb);
    }
#pragma unroll
    for (int kb = 0; kb < 4; ++kb) {
        wU1[kb] = loadW(Wu1, 114, kb);
        wR1[kb] = loadW(Wr1, 114, kb);
        wN1[kb] = loadW(Wn1, 114, kb);
    }
    // vol B-frag (only wave 0 uses it): column 0 = Wd, cols 1..15 = 0.
    // hi-only: vol is a leaf output, lo terms contribute ~0.03 abs.
    half8 vwd[2];
#pragma unroll
    for (int kb = 0; kb < 2; ++kb)
#pragma unroll
        for (int j = 0; j < 8; ++j) {
            int k = kb * 32 + quad * 8 + j;
            vwd[kb][j] = (_Float16)((col16 == 0) ? Wd[k] : 0.0f);
        }
    const float bo1v = bo1[ncol], bo2v = bo2[ncol];
    const float bu1v = bu1[ncol], bu2v = bu2[ncol];
    const float br1v = br1[ncol], br2v = br2[ncol];
    const float bn1v = bn1[ncol], bn2v = bn2[ncol];

    // ---- presence masks (dedup == reference's presence): wave wv owns
    // rows 2wv..2wv+1 for feat loading ----
    unsigned long long mLo[2], mHi[2];
    const float* dPtr[2];
#pragma unroll
    for (int r4 = 0; r4 < 2; ++r4) {
        int b = rowBase + 2 * wv + r4;
        int v = tsteps[b * 64 + lane];
        unsigned long long lo = (v < 64) ? (1ull << v) : 0ull;
        unsigned long long hi = (v >= 64) ? (1ull << (v - 64)) : 0ull;
#pragma unroll
        for (int st = 1; st < 64; st <<= 1) {
            lo |= __shfl_xor(lo, st);
            hi |= __shfl_xor(hi, st);
        }
        mLo[r4] = lo; mHi[r4] = hi;
        dPtr[r4] = data + (size_t)b * 6400;
    }
    __syncthreads();

    floatx4 pc = {0.f, 0.f, 0.f, 0.f};   // fp32 state, C-layout slice
    const floatx4 z = {0.f, 0.f, 0.f, 0.f};

    const int aOff  = col16 * 72 + quad * 8;   // stride-72 A-frag base
    const int aOffH = col16 * 136 + quad * 8;  // stride-136 A-frag base

    // ---- prefetch step 0's feat loads ----
    bool hasU[2];
    float fv[2], mv[2];
#pragma unroll
    for (int r4 = 0; r4 < 2; ++r4) {
        hasU[r4] = (mLo[r4] & 1ull) != 0ull;
        fv[r4] = 0.f; mv[r4] = 0.f;
        if (hasU[r4]) {
            const float* dp = dPtr[r4];
            dPtr[r4] = dp + 100;
            if (lane < 50) { fv[r4] = dp[lane]; mv[r4] = dp[50 + lane]; }
        }
    }

    for (int i = 0; i < 128; ++i) {
        // ---- A) issue NEXT step's feat loads (consumed next iteration;
        //      the vmcnt(0) drain at B1 gives them the mm1 segment to land) ----
        const int ip = i + 1;
        bool hasN[2];
        float fN[2], mN[2];
#pragma unroll
        for (int r4 = 0; r4 < 2; ++r4) {
            unsigned long long mm =
                (ip < 64) ? (mLo[r4] >> ip)
                          : ((ip < 128) ? (mHi[r4] >> (ip - 64)) : 0ull);
            hasN[r4] = (mm & 1ull) != 0ull;
            fN[r4] = 0.f; mN[r4] = 0.f;
            if (hasN[r4]) {
                const float* dp = dPtr[r4];
                dPtr[r4] = dp + 100;
                if (lane < 50) { fN[r4] = dp[lane]; mN[r4] = dp[50 + lane]; }
            }
        }

        // ---- mm1: t = tanh(y @ Wo1 + bo1); wave 0: vol = y @ Wd + bd ----
        {
            half8 a0h = *(const half8*)&sYh[aOff];
            half8 a0l = *(const half8*)&sYl[aOff];
            half8 a1h = *(const half8*)&sYh[aOff + 32];
            half8 a1l = *(const half8*)&sYl[aOff + 32];
            floatx4 cb = {bo1v, bo1v, bo1v, bo1v};
            floatx4 hh = MFMA(a1h, wO1[1].h, MFMA(a0h, wO1[0].h, cb));
            floatx4 hl = MFMA(a1h, wO1[1].l, MFMA(a0h, wO1[0].l, z));
            floatx4 lh = MFMA(a1l, wO1[1].h, MFMA(a0l, wO1[0].h, z));
            if (wv == 0) {
                floatx4 v = MFMA(a1h, vwd[1], MFMA(a0h, vwd[0], z));
                if (col16 == 0) {
#pragma unroll
                    for (int r = 0; r < 4; ++r)
                        sVol[(quad * 4 + r) * 132 + i] = v[r] + bdv;
                }
            }
            floatx4 acc = hh + (hl + lh);
#pragma unroll
            for (int r = 0; r < 4; ++r) {
                float t = tanhf_fast(acc[r]);
                _Float16 h = (_Float16)t;
                int idx = (quad * 4 + r) * 72 + ncol;
                sTh[idx] = h;
                sTl[idx] = (_Float16)(t - (float)h);
            }
        }
        __syncthreads();                                   // B1

        // ---- mm2: y1 = y + t @ Wo2 + bo2 ----
        floatx4 y1;
        {
            half8 t0h = *(const half8*)&sTh[aOff];
            half8 t0l = *(const half8*)&sTl[aOff];
            half8 t1h = *(const half8*)&sTh[aOff + 32];
            half8 t1l = *(const half8*)&sTl[aOff + 32];
            floatx4 cb = {bo2v, bo2v, bo2v, bo2v};
            floatx4 hh = MFMA(t1h, wO2[1].h, MFMA(t0h, wO2[0].h, cb));
            floatx4 hl = MFMA(t1h, wO2[1].l, MFMA(t0h, wO2[0].l, z));
            floatx4 lh = MFMA(t1l, wO2[1].h, MFMA(t0l, wO2[0].h, z));
            floatx4 acc = hh + (hl + lh);
#pragma unroll
            for (int r = 0; r < 4; ++r) {
                y1[r] = pc[r] + acc[r];
                _Float16 h = (_Float16)y1[r];
                int idx = (quad * 4 + r) * 136 + ncol;
                sYCh[idx] = h;
                sYCl[idx] = (_Float16)(y1[r] - (float)h);
            }
        }

        // ---- C) feat commit (hi+lo, prefetched last iter) + ballot flags ----
#pragma unroll
        for (int r4 = 0; r4 < 2; ++r4) {
            int row = 2 * wv + r4;
            if (hasU[r4]) {
                if (lane < 50) {
                    float f = fv[r4];
                    _Float16 h = (_Float16)f;
                    _Float16 l = (_Float16)(f - (float)h);
                    int idx = row * 136 + 64 + lane;
                    sYCh[idx] = h; sYCl[idx] = l;
                    sCCh[idx] = h; sCCl[idx] = l;
                }
                unsigned long long bal = __ballot(mv[r4] > 0.f);
                if (lane == 0) sFlg[row] = bal ? 1u : 0u;
            } else if (lane == 0) {
                sFlg[row] = 0u;
            }
        }
        __syncthreads();                                   // B2

        // ---- mm3: hu = tanh(yc@Wu1+bu1), hr = tanh(yc@Wr1+br1), K=128 ----
        {
            half8 ah0 = *(const half8*)&sYCh[aOffH];
            half8 ah1 = *(const half8*)&sYCh[aOffH + 32];
            half8 ah2 = *(const half8*)&sYCh[aOffH + 64];
            half8 ah3 = *(const half8*)&sYCh[aOffH + 96];
            half8 al0 = *(const half8*)&sYCl[aOffH];
            half8 al1 = *(const half8*)&sYCl[aOffH + 32];
            half8 al2 = *(const half8*)&sYCl[aOffH + 64];
            half8 al3 = *(const half8*)&sYCl[aOffH + 96];
            floatx4 cu = {bu1v, bu1v, bu1v, bu1v};
            floatx4 cr = {br1v, br1v, br1v, br1v};
            floatx4 uhh = MFMA(ah3, wU1[3].h, MFMA(ah2, wU1[2].h,
                          MFMA(ah1, wU1[1].h, MFMA(ah0, wU1[0].h, cu))));
            floatx4 uhl = MFMA(ah3, wU1[3].l, MFMA(ah2, wU1[2].l,
                          MFMA(ah1, wU1[1].l, MFMA(ah0, wU1[0].l, z))));
            floatx4 ulh = MFMA(al3, wU1[3].h, MFMA(al2, wU1[2].h,
                          MFMA(al1, wU1[1].h, MFMA(al0, wU1[0].h, z))));
            floatx4 rhh = MFMA(ah3, wR1[3].h, MFMA(ah2, wR1[2].h,
                          MFMA(ah1, wR1[1].h, MFMA(ah0, wR1[0].h, cr))));
            floatx4 rhl = MFMA(ah3, wR1[3].l, MFMA(ah2, wR1[2].l,
                          MFMA(ah1, wR1[1].l, MFMA(ah0, wR1[0].l, z))));
            floatx4 rlh = MFMA(al3, wR1[3].h, MFMA(al2, wR1[2].h,
                          MFMA(al1, wR1[1].h, MFMA(al0, wR1[0].h, z))));
            floatx4 aU = uhh + (uhl + ulh);
            floatx4 aR = rhh + (rhl + rlh);
#pragma unroll
            for (int r = 0; r < 4; ++r) {
                float tu = tanhf_fast(aU[r]);
                float tr = tanhf_fast(aR[r]);
                int idx = (quad * 4 + r) * 72 + ncol;
                _Float16 hu = (_Float16)tu, hr = (_Float16)tr;
                sHuh[idx] = hu; sHul[idx] = (_Float16)(tu - (float)hu);
                sHrh[idx] = hr; sHrl[idx] = (_Float16)(tr - (float)hr);
            }
        }
        __syncthreads();                                   // B3

        // ---- mm4: u = sig(hu@Wu2+bu2), r = sig(hr@Wr2+br2); cc = y1*r ----
        floatx4 uG;
        {
            half8 u0h = *(const half8*)&sHuh[aOff];
            half8 u0l = *(const half8*)&sHul[aOff];
            half8 u1h = *(const half8*)&sHuh[aOff + 32];
            half8 u1l = *(const half8*)&sHul[aOff + 32];
            floatx4 cu = {bu2v, bu2v, bu2v, bu2v};
            floatx4 cr = {br2v, br2v, br2v, br2v};
            floatx4 au = MFMA(u1h, wU2[1].h, MFMA(u0h, wU2[0].h, cu))
                       + (MFMA(u1h, wU2[1].l, MFMA(u0h, wU2[0].l, z))
                        + MFMA(u1l, wU2[1].h, MFMA(u0l, wU2[0].h, z)));
            half8 r0h = *(const half8*)&sHrh[aOff];
            half8 r0l = *(const half8*)&sHrl[aOff];
            half8 r1h = *(const half8*)&sHrh[aOff + 32];
            half8 r1l = *(const half8*)&sHrl[aOff + 32];
            floatx4 ar = MFMA(r1h, wR2[1].h, MFMA(r0h, wR2[0].h, cr))
                       + (MFMA(r1h, wR2[1].l, MFMA(r0h, wR2[0].l, z))
                        + MFMA(r1l, wR2[1].h, MFMA(r0l, wR2[0].h, z)));
#pragma unroll
            for (int r = 0; r < 4; ++r) {
                uG[r] = sigmoidf_fast(au[r]);
                float rg = sigmoidf_fast(ar[r]);
                float cc = y1[r] * rg;
                _Float16 h = (_Float16)cc;
                int idx = (quad * 4 + r) * 136 + ncol;
                sCCh[idx] = h;
                sCCl[idx] = (_Float16)(cc - (float)h);
            }
        }
        __syncthreads();                                   // B4

        // ---- mm5: hn = tanh(cc @ Wn1 + bn1), K=128 (into sT alias) ----
        {
            half8 ah0 = *(const half8*)&sCCh[aOffH];
            half8 ah1 = *(const half8*)&sCCh[aOffH + 32];
            half8 ah2 = *(const half8*)&sCCh[aOffH + 64];
            half8 ah3 = *(const half8*)&sCCh[aOffH + 96];
            half8 al0 = *(const half8*)&sCCl[aOffH];
            half8 al1 = *(const half8*)&sCCl[aOffH + 32];
            half8 al2 = *(const half8*)&sCCl[aOffH + 64];
            half8 al3 = *(const half8*)&sCCl[aOffH + 96];
            floatx4 cn = {bn1v, bn1v, bn1v, bn1v};
            floatx4 nhh = MFMA(ah3, wN1[3].h, MFMA(ah2, wN1[2].h,
                          MFMA(ah1, wN1[1].h, MFMA(ah0, wN1[0].h, cn))));
            floatx4 nhl = MFMA(ah3, wN1[3].l, MFMA(ah2, wN1[2].l,
                          MFMA(ah1, wN1[1].l, MFMA(ah0, wN1[0].l, z))));
            floatx4 nlh = MFMA(al3, wN1[3].h, MFMA(al2, wN1[2].h,
                          MFMA(al1, wN1[1].h, MFMA(al0, wN1[0].h, z))));
            floatx4 aN = nhh + (nhl + nlh);
#pragma unroll
            for (int r = 0; r < 4; ++r) {
                float t = tanhf_fast(aN[r]);
                _Float16 h = (_Float16)t;
                int idx = (quad * 4 + r) * 72 + ncol;
                sTh[idx] = h;
                sTl[idx] = (_Float16)(t - (float)h);
            }
        }
        __syncthreads();                                   // B5

        // ---- mm6: ns = hn@Wn2 + bn2; blend; state update ----
        {
            half8 n0h = *(const half8*)&sTh[aOff];
            half8 n0l = *(const half8*)&sTl[aOff];
            half8 n1h = *(const half8*)&sTh[aOff + 32];
            half8 n1l = *(const half8*)&sTl[aOff + 32];
            floatx4 cn = {bn2v, bn2v, bn2v, bn2v};
            floatx4 acc = MFMA(n1h, wN2[1].h, MFMA(n0h, wN2[0].h, cn))
                        + (MFMA(n1h, wN2[1].l, MFMA(n0h, wN2[0].l, z))
                         + MFMA(n1l, wN2[1].h, MFMA(n0l, wN2[0].h, z)));
#pragma unroll
            for (int r = 0; r < 4; ++r) {
                float ns = acc[r];
                float ny = (1.0f - uG[r]) * ns + uG[r] * y1[r];
                unsigned ap = sFlg[quad * 4 + r];          // upd && m
                float nY = ap ? ny : y1[r];                // select: NaN-safe
                pc[r] = nY;
                int rr = quad * 4 + r;
                _Float16 h = (_Float16)nY;
                sYh[rr * 72 + ncol] = h;
                sYl[rr * 72 + ncol] = (_Float16)(nY - (float)h);
            }
        }
        __syncthreads();                                   // B6

        // ---- rotate prefetched feat ----
#pragma unroll
        for (int r4 = 0; r4 < 2; ++r4) {
            hasU[r4] = hasN[r4];
            fv[r4] = fN[r4];
            mv[r4] = mN[r4];
        }
    }

    // ---- epilogue (only real rows 0..7 stored) ----
    if (quad < 2) {
#pragma unroll
        for (int r = 0; r < 4; ++r) {
            int b = rowBase + quad * 4 + r;
            out[(size_t)b * 64 + ncol] = pc[r];
        }
    }
    float* out1 = out + (size_t)4096 * 64;
    float* out2 = out1 + (size_t)4096 * 63;
#pragma unroll
    for (int r4 = 0; r4 < 2; ++r4) {
        int row = 2 * wv + r4;
        int b = rowBase + row;
        if (lane < 63) {
            int t0 = tsteps[b * 64 + lane];
            int t1 = tsteps[b * 64 + lane + 1];
            int iv = t0 < 126 ? t0 : 126;
            out1[(size_t)b * 63 + lane] = sVol[row * 132 + iv + 1];
            out2[(size_t)b * 63 + lane] = (float)(t1 - t0);
        }
    }
}

extern "C" void kernel_launch(void* const* d_in, const int* in_sizes, int n_in,
                              void* d_out, int out_size, void* d_ws, size_t ws_size,
                              hipStream_t stream) {
    const float* data   = (const float*)d_in[0];
    const int*   tsteps = (const int*)  d_in[1];
    const float* Wu1 = (const float*)d_in[2];  const float* bu1 = (const float*)d_in[3];
    const float* Wu2 = (const float*)d_in[4];  const float* bu2 = (const float*)d_in[5];
    const float* Wr1 = (const float*)d_in[6];  const float* br1 = (const float*)d_in[7];
    const float* Wr2 = (const float*)d_in[8];  const float* br2 = (const float*)d_in[9];
    const float* Wn1 = (const float*)d_in[10]; const float* bn1 = (const float*)d_in[11];
    const float* Wn2 = (const float*)d_in[12]; const float* bn2 = (const float*)d_in[13];
    const float* Wo1 = (const float*)d_in[14]; const float* bo1 = (const float*)d_in[15];
    const float* Wo2 = (const float*)d_in[16]; const float* bo2 = (const float*)d_in[17];
    const float* Wd  = (const float*)d_in[18]; const float* bd  = (const float*)d_in[19];
    float* out = (float*)d_out;

    lobrm_fused<<<dim3(512), dim3(256), 0, stream>>>(
        data, tsteps, Wu1, bu1, Wu2, bu2, Wr1, br1, Wr2, br2,
        Wn1, bn1, Wn2, bn2, Wo1, bo1, Wo2, bo2, Wd, bd, out);
}

// Round 3
// 786.073 us; speedup vs baseline: 2.0217x; 1.2740x over previous
//
#include <hip/hip_runtime.h>

// LOBRM fused recurrence on gfx950 — fp16 hi/lo split-precision MFMA, R11.
// R11 = K-SPLIT restructure. R9/R10 taught: (1) occupancy boundary is total
// arch+AGPR regs (192+~80 failed, 128+128 co-resided); (2) M-splitting
// doubles work (garbage rows) so it can at best tie R8's 488us. The only
// work-conserving way to 2 waves/SIMD: 8 waves/block (512 thr), wave pair
// (wq, kh) K-splits every matmul. Each wave: half the MFMAs, half the
// ds_reads, HALF THE PINNED WEIGHTS (~96 regs -> total well under 256).
// Partial sums exchanged via 4KB f32 LDS buffers; finalize (add partner +
// tanh + fp16 hi/lo store) row-split across the pair (kh0->rows 0-7,
// kh1->rows 8-15) so VALU is conserved and y1/uG/pc live in one thread.
// 2 barriers/segment (12/step). Grid 256 = 1 block/CU, M=16 real rows,
// zero duplicated work, 2 real waves/SIMD to fill the ~55% stall fraction.
//  - feat global loads prefetched ONE STEP AHEAD (2 rows/wave)
//  - bias folded into kh=0 wave's MFMA C-init (counted exactly once)
//  - __ballot flag (msk half of data is abs()'d: sum>0 <=> any>0)
//  - vol = hh term only, full-K on wave 0 (leaf output, err ~0.03 << 0.705)
//  - sT aliased for Hn (disjoint lifetimes)

typedef __attribute__((ext_vector_type(8))) _Float16 half8;  // 8 fp16 = 4 VGPRs
typedef __attribute__((ext_vector_type(4))) float floatx4;   // MFMA C/D

#define MFMA(a, b, c) __builtin_amdgcn_mfma_f32_16x16x32_f16((a), (b), (c), 0, 0, 0)

__device__ __forceinline__ float tanhf_fast(float x) {
    float e = __builtin_exp2f(x * 2.8853900817779268f);  // e^{2x}
    return 1.0f - 2.0f / (e + 1.0f);                     // inf-safe: ->1 / -1
}
__device__ __forceinline__ float sigmoidf_fast(float x) {
    float e = __builtin_exp2f(x * -1.4426950408889634f); // e^{-x}
    return 1.0f / (1.0f + e);
}

struct W2 { half8 h, l; };

__global__ __launch_bounds__(512)
void lobrm_fused(const float* __restrict__ data,   // (4096,64,100)
                 const int*   __restrict__ tsteps, // (4096,64)
                 const float* __restrict__ Wu1, const float* __restrict__ bu1,
                 const float* __restrict__ Wu2, const float* __restrict__ bu2,
                 const float* __restrict__ Wr1, const float* __restrict__ br1,
                 const float* __restrict__ Wr2, const float* __restrict__ br2,
                 const float* __restrict__ Wn1, const float* __restrict__ bn1,
                 const float* __restrict__ Wn2, const float* __restrict__ bn2,
                 const float* __restrict__ Wo1, const float* __restrict__ bo1,
                 const float* __restrict__ Wo2, const float* __restrict__ bo2,
                 const float* __restrict__ Wd,  const float* __restrict__ bd,
                 float* __restrict__ out)
{
    // fp16 hi/lo activation buffers. Row strides 72/136 halfs: 16B-aligned.
    // sTh/sTl double as Hn buffers (T: mm1->mm2, Hn: mm5->mm6; disjoint).
    __shared__ __align__(16) _Float16 sYh [16 * 72],  sYl [16 * 72];
    __shared__ __align__(16) _Float16 sTh [16 * 72],  sTl [16 * 72];
    __shared__ __align__(16) _Float16 sHuh[16 * 72],  sHul[16 * 72];
    __shared__ __align__(16) _Float16 sHrh[16 * 72],  sHrl[16 * 72];
    __shared__ __align__(16) _Float16 sYCh[16 * 136], sYCl[16 * 136]; // [y1|feat|0]
    __shared__ __align__(16) _Float16 sCCh[16 * 136], sCCl[16 * 136]; // [y1*r|feat|0]
    __shared__ float    sVol[16 * 132];   // vol per row per step
    __shared__ float    sPu [16 * 66];    // K-split partials (stride 66: bank-stagger)
    __shared__ float    sPr [16 * 66];
    __shared__ unsigned sFlg[16];         // apply = upd && m, per row

    const int tid   = threadIdx.x;
    const int lane  = tid & 63;
    const int wv    = tid >> 6;          // wave 0..7
    const int wq    = wv & 3;            // column quarter (N-slice)
    const int kh    = wv >> 2;           // K-half owned by this wave
    const int col16 = lane & 15;
    const int quad  = lane >> 4;
    const int ncol  = wq * 16 + col16;   // output column 0..63
    const bool fin  = ((quad >> 1) == kh);  // this thread finalizes its 4 rows
    const int rowBase = blockIdx.x * 16;

    // ---- prologue: zero state + pad regions (pads must stay 0 forever) ----
    for (int x = tid; x < 16 * 72; x += 512) {
        sYh[x] = (_Float16)0.f; sYl[x] = (_Float16)0.f;
    }
    for (int x = tid; x < 16 * 136; x += 512) {
        sYCh[x] = (_Float16)0.f; sYCl[x] = (_Float16)0.f;
        sCCh[x] = (_Float16)0.f; sCCl[x] = (_Float16)0.f;
    }
    const float bdv = bd[0];

    // ---- weight hi/lo B-fragments: ONLY this wave's K-half ----
    // B-frag: lane holds B[k = kbg*32 + quad*8 + j][n = ncol]
    auto loadW = [&](const float* W, int Kw, int kbg) -> W2 {
        W2 f;
#pragma unroll
        for (int j = 0; j < 8; ++j) {
            int k = kbg * 32 + quad * 8 + j;
            float v = (k < Kw) ? W[k * 64 + ncol] : 0.0f;
            _Float16 h = (_Float16)v;
            f.h[j] = h;
            f.l[j] = (_Float16)(v - (float)h);
        }
        return f;
    };
    W2 wO1 = loadW(Wo1, 64, kh);
    W2 wO2 = loadW(Wo2, 64, kh);
    W2 wU2 = loadW(Wu2, 64, kh);
    W2 wR2 = loadW(Wr2, 64, kh);
    W2 wN2 = loadW(Wn2, 64, kh);
    W2 wU1[2], wR1[2], wN1[2];
#pragma unroll
    for (int t = 0; t < 2; ++t) {
        wU1[t] = loadW(Wu1, 114, kh * 2 + t);
        wR1[t] = loadW(Wr1, 114, kh * 2 + t);
        wN1[t] = loadW(Wn1, 114, kh * 2 + t);
    }
    // vol B-frag (wave 0 computes vol full-K): col 0 = Wd, cols 1..15 = 0.
    half8 vwd[2];
#pragma unroll
    for (int kb = 0; kb < 2; ++kb)
#pragma unroll
        for (int j = 0; j < 8; ++j) {
            int k = kb * 32 + quad * 8 + j;
            vwd[kb][j] = (_Float16)((col16 == 0) ? Wd[k] : 0.0f);
        }
    // biases: folded into kh=0's MFMA C-init (counted once across the pair)
    const float cO1 = kh ? 0.f : bo1[ncol];
    const float cO2 = kh ? 0.f : bo2[ncol];
    const float cU1 = kh ? 0.f : bu1[ncol];
    const float cR1 = kh ? 0.f : br1[ncol];
    const float cN1 = kh ? 0.f : bn1[ncol];
    const float cU2 = kh ? 0.f : bu2[ncol];
    const float cR2 = kh ? 0.f : br2[ncol];
    const float cN2 = kh ? 0.f : bn2[ncol];

    // ---- presence masks: wave wv owns rows 2wv..2wv+1 for feat loading ----
    unsigned long long mLo[2], mHi[2];
    const float* dPtr[2];
#pragma unroll
    for (int r4 = 0; r4 < 2; ++r4) {
        int b = rowBase + 2 * wv + r4;
        int v = tsteps[b * 64 + lane];
        unsigned long long lo = (v < 64) ? (1ull << v) : 0ull;
        unsigned long long hi = (v >= 64) ? (1ull << (v - 64)) : 0ull;
#pragma unroll
        for (int st = 1; st < 64; st <<= 1) {
            lo |= __shfl_xor(lo, st);
            hi |= __shfl_xor(hi, st);
        }
        mLo[r4] = lo; mHi[r4] = hi;
        dPtr[r4] = data + (size_t)b * 6400;
    }
    __syncthreads();

    floatx4 pc = {0.f, 0.f, 0.f, 0.f};   // fp32 state (valid in fin threads)
    const floatx4 z = {0.f, 0.f, 0.f, 0.f};

    // A-frag bases: this wave's K-half only
    const int aOff  = col16 * 72  + kh * 32 + quad * 8;  // K=64 mats
    const int aOffH = col16 * 136 + kh * 64 + quad * 8;  // K=128 mats
    const int aVol  = col16 * 72  + 32      + quad * 8;  // vol 2nd half (wv0)
    const int pOff  = quad * 4 * 66 + ncol;              // partial-buf base

    // ---- prefetch step 0's feat loads ----
    bool hasU[2];
    float fv[2], mv[2];
#pragma unroll
    for (int r4 = 0; r4 < 2; ++r4) {
        hasU[r4] = (mLo[r4] & 1ull) != 0ull;
        fv[r4] = 0.f; mv[r4] = 0.f;
        if (hasU[r4]) {
            const float* dp = dPtr[r4];
            dPtr[r4] = dp + 100;
            if (lane < 50) { fv[r4] = dp[lane]; mv[r4] = dp[50 + lane]; }
        }
    }

    for (int i = 0; i < 128; ++i) {
        // ---- A) issue NEXT step's feat loads (consumed next iteration) ----
        const int ip = i + 1;
        bool hasN[2];
        float fN[2], mN[2];
#pragma unroll
        for (int r4 = 0; r4 < 2; ++r4) {
            unsigned long long mm =
                (ip < 64) ? (mLo[r4] >> ip)
                          : ((ip < 128) ? (mHi[r4] >> (ip - 64)) : 0ull);
            hasN[r4] = (mm & 1ull) != 0ull;
            fN[r4] = 0.f; mN[r4] = 0.f;
            if (hasN[r4]) {
                const float* dp = dPtr[r4];
                dPtr[r4] = dp + 100;
                if (lane < 50) { fN[r4] = dp[lane]; mN[r4] = dp[50 + lane]; }
            }
        }

        // ---- mm1: t = tanh(y @ Wo1 + bo1); wave 0: vol = y @ Wd + bd ----
        {
            half8 a0h = *(const half8*)&sYh[aOff];
            half8 a0l = *(const half8*)&sYl[aOff];
            floatx4 ci = {cO1, cO1, cO1, cO1};
            floatx4 p = MFMA(a0h, wO1.h, ci);
            p = MFMA(a0h, wO1.l, p);
            p = MFMA(a0l, wO1.h, p);
            if (wv == 0) {
                half8 a1h = *(const half8*)&sYh[aVol];
                floatx4 v = MFMA(a1h, vwd[1], MFMA(a0h, vwd[0], z));
                if (col16 == 0) {
#pragma unroll
                    for (int r = 0; r < 4; ++r)
                        sVol[(quad * 4 + r) * 132 + i] = v[r] + bdv;
                }
            }
            if (!fin) {
#pragma unroll
                for (int r = 0; r < 4; ++r) sPu[pOff + r * 66] = p[r];
            }
            __syncthreads();                               // B1a
            if (fin) {
#pragma unroll
                for (int r = 0; r < 4; ++r) {
                    float t = tanhf_fast(p[r] + sPu[pOff + r * 66]);
                    _Float16 h = (_Float16)t;
                    int idx = (quad * 4 + r) * 72 + ncol;
                    sTh[idx] = h;
                    sTl[idx] = (_Float16)(t - (float)h);
                }
            }
            __syncthreads();                               // B1b
        }

        // ---- mm2: y1 = y + t @ Wo2 + bo2 (+ feat commit overlapped) ----
        floatx4 y1;                                        // valid in fin
        {
            half8 t0h = *(const half8*)&sTh[aOff];
            half8 t0l = *(const half8*)&sTl[aOff];
            floatx4 ci = {cO2, cO2, cO2, cO2};
            floatx4 p = MFMA(t0h, wO2.h, ci);
            p = MFMA(t0h, wO2.l, p);
            p = MFMA(t0l, wO2.h, p);
            if (!fin) {
#pragma unroll
                for (int r = 0; r < 4; ++r) sPu[pOff + r * 66] = p[r];
            }
            // feat commit (prefetched last iter) + ballot flags — writes
            // sYC/sCC cols 64.. and sFlg; consumers are past barriers.
#pragma unroll
            for (int r4 = 0; r4 < 2; ++r4) {
                int row = 2 * wv + r4;
                if (hasU[r4]) {
                    if (lane < 50) {
                        float f = fv[r4];
                        _Float16 h = (_Float16)f;
                        _Float16 l = (_Float16)(f - (float)h);
                        int idx = row * 136 + 64 + lane;
                        sYCh[idx] = h; sYCl[idx] = l;
                        sCCh[idx] = h; sCCl[idx] = l;
                    }
                    unsigned long long bal = __ballot(mv[r4] > 0.f);
                    if (lane == 0) sFlg[row] = bal ? 1u : 0u;
                } else if (lane == 0) {
                    sFlg[row] = 0u;
                }
            }
            __syncthreads();                               // B2a
            if (fin) {
#pragma unroll
                for (int r = 0; r < 4; ++r) {
                    y1[r] = pc[r] + (p[r] + sPu[pOff + r * 66]);
                    _Float16 h = (_Float16)y1[r];
                    int idx = (quad * 4 + r) * 136 + ncol;
                    sYCh[idx] = h;
                    sYCl[idx] = (_Float16)(y1[r] - (float)h);
                }
            }
            __syncthreads();                               // B2b
        }

        // ---- mm3: hu = tanh(yc@Wu1+bu1), hr = tanh(yc@Wr1+br1), K/2=64 ----
        {
            half8 ah0 = *(const half8*)&sYCh[aOffH];
            half8 ah1 = *(const half8*)&sYCh[aOffH + 32];
            half8 al0 = *(const half8*)&sYCl[aOffH];
            half8 al1 = *(const half8*)&sYCl[aOffH + 32];
            floatx4 cu = {cU1, cU1, cU1, cU1};
            floatx4 cr = {cR1, cR1, cR1, cR1};
            floatx4 u = MFMA(ah0, wU1[0].h, cu);
            u = MFMA(ah1, wU1[1].h, u);
            u = MFMA(ah0, wU1[0].l, u);
            u = MFMA(ah1, wU1[1].l, u);
            u = MFMA(al0, wU1[0].h, u);
            u = MFMA(al1, wU1[1].h, u);
            floatx4 q = MFMA(ah0, wR1[0].h, cr);
            q = MFMA(ah1, wR1[1].h, q);
            q = MFMA(ah0, wR1[0].l, q);
            q = MFMA(ah1, wR1[1].l, q);
            q = MFMA(al0, wR1[0].h, q);
            q = MFMA(al1, wR1[1].h, q);
            if (!fin) {
#pragma unroll
                for (int r = 0; r < 4; ++r) {
                    sPu[pOff + r * 66] = u[r];
                    sPr[pOff + r * 66] = q[r];
                }
            }
            __syncthreads();                               // B3a
            if (fin) {
#pragma unroll
                for (int r = 0; r < 4; ++r) {
                    float tu = tanhf_fast(u[r] + sPu[pOff + r * 66]);
                    float tr = tanhf_fast(q[r] + sPr[pOff + r * 66]);
                    int idx = (quad * 4 + r) * 72 + ncol;
                    _Float16 hu = (_Float16)tu, hr = (_Float16)tr;
                    sHuh[idx] = hu; sHul[idx] = (_Float16)(tu - (float)hu);
                    sHrh[idx] = hr; sHrl[idx] = (_Float16)(tr - (float)hr);
                }
            }
            __syncthreads();                               // B3b
        }

        // ---- mm4: u = sig(hu@Wu2+bu2), r = sig(hr@Wr2+br2); cc = y1*r ----
        floatx4 uG;                                        // valid in fin
        {
            half8 u0h = *(const half8*)&sHuh[aOff];
            half8 u0l = *(const half8*)&sHul[aOff];
            half8 r0h = *(const half8*)&sHrh[aOff];
            half8 r0l = *(const half8*)&sHrl[aOff];
            floatx4 cu = {cU2, cU2, cU2, cU2};
            floatx4 cr = {cR2, cR2, cR2, cR2};
            floatx4 au = MFMA(u0h, wU2.h, cu);
            au = MFMA(u0h, wU2.l, au);
            au = MFMA(u0l, wU2.h, au);
            floatx4 ar = MFMA(r0h, wR2.h, cr);
            ar = MFMA(r0h, wR2.l, ar);
            ar = MFMA(r0l, wR2.h, ar);
            if (!fin) {
#pragma unroll
                for (int r = 0; r < 4; ++r) {
                    sPu[pOff + r * 66] = au[r];
                    sPr[pOff + r * 66] = ar[r];
                }
            }
            __syncthreads();                               // B4a
            if (fin) {
#pragma unroll
                for (int r = 0; r < 4; ++r) {
                    uG[r] = sigmoidf_fast(au[r] + sPu[pOff + r * 66]);
                    float rg = sigmoidf_fast(ar[r] + sPr[pOff + r * 66]);
                    float cc = y1[r] * rg;
                    _Float16 h = (_Float16)cc;
                    int idx = (quad * 4 + r) * 136 + ncol;
                    sCCh[idx] = h;
                    sCCl[idx] = (_Float16)(cc - (float)h);
                }
            }
            __syncthreads();                               // B4b
        }

        // ---- mm5: hn = tanh(cc @ Wn1 + bn1), K/2=64 (into sT alias) ----
        {
            half8 ah0 = *(const half8*)&sCCh[aOffH];
            half8 ah1 = *(const half8*)&sCCh[aOffH + 32];
            half8 al0 = *(const half8*)&sCCl[aOffH];
            half8 al1 = *(const half8*)&sCCl[aOffH + 32];
            floatx4 cn = {cN1, cN1, cN1, cN1};
            floatx4 u = MFMA(ah0, wN1[0].h, cn);
            u = MFMA(ah1, wN1[1].h, u);
            u = MFMA(ah0, wN1[0].l, u);
            u = MFMA(ah1, wN1[1].l, u);
            u = MFMA(al0, wN1[0].h, u);
            u = MFMA(al1, wN1[1].h, u);
            if (!fin) {
#pragma unroll
                for (int r = 0; r < 4; ++r) sPu[pOff + r * 66] = u[r];
            }
            __syncthreads();                               // B5a
            if (fin) {
#pragma unroll
                for (int r = 0; r < 4; ++r) {
                    float t = tanhf_fast(u[r] + sPu[pOff + r * 66]);
                    _Float16 h = (_Float16)t;
                    int idx = (quad * 4 + r) * 72 + ncol;
                    sTh[idx] = h;
                    sTl[idx] = (_Float16)(t - (float)h);
                }
            }
            __syncthreads();                               // B5b
        }

        // ---- mm6: ns = hn@Wn2 + bn2; blend; state update ----
        {
            half8 n0h = *(const half8*)&sTh[aOff];
            half8 n0l = *(const half8*)&sTl[aOff];
            floatx4 ci = {cN2, cN2, cN2, cN2};
            floatx4 p = MFMA(n0h, wN2.h, ci);
            p = MFMA(n0h, wN2.l, p);
            p = MFMA(n0l, wN2.h, p);
            if (!fin) {
#pragma unroll
                for (int r = 0; r < 4; ++r) sPu[pOff + r * 66] = p[r];
            }
            __syncthreads();                               // B6a
            if (fin) {
#pragma unroll
                for (int r = 0; r < 4; ++r) {
                    float ns = p[r] + sPu[pOff + r * 66];
                    float ny = (1.0f - uG[r]) * ns + uG[r] * y1[r];
                    unsigned ap = sFlg[quad * 4 + r];      // upd && m
                    float nY = ap ? ny : y1[r];            // select: NaN-safe
                    pc[r] = nY;
                    int idx = (quad * 4 + r) * 72 + ncol;
                    _Float16 h = (_Float16)nY;
                    sYh[idx] = h;
                    sYl[idx] = (_Float16)(nY - (float)h);
                }
            }
            __syncthreads();                               // B6b
        }

        // ---- rotate prefetched feat ----
#pragma unroll
        for (int r4 = 0; r4 < 2; ++r4) {
            hasU[r4] = hasN[r4];
            fv[r4] = fN[r4];
            mv[r4] = mN[r4];
        }
    }

    // ---- epilogue: fin threads own their 4 rows' final state ----
    if (fin) {
#pragma unroll
        for (int r = 0; r < 4; ++r) {
            int b = rowBase + quad * 4 + r;
            out[(size_t)b * 64 + ncol] = pc[r];
        }
    }
    float* out1 = out + (size_t)4096 * 64;
    float* out2 = out1 + (size_t)4096 * 63;
#pragma unroll
    for (int r4 = 0; r4 < 2; ++r4) {
        int row = 2 * wv + r4;
        int b = rowBase + row;
        if (lane < 63) {
            int t0 = tsteps[b * 64 + lane];
            int t1 = tsteps[b * 64 + lane + 1];
            int iv = t0 < 126 ? t0 : 126;
            out1[(size_t)b * 63 + lane] = sVol[row * 132 + iv + 1];
            out2[(size_t)b * 63 + lane] = (float)(t1 - t0);
        }
    }
}

extern "C" void kernel_launch(void* const* d_in, const int* in_sizes, int n_in,
                              void* d_out, int out_size, void* d_ws, size_t ws_size,
                              hipStream_t stream) {
    const float* data   = (const float*)d_in[0];
    const int*   tsteps = (const int*)  d_in[1];
    const float* Wu1 = (const float*)d_in[2];  const float* bu1 = (const float*)d_in[3];
    const float* Wu2 = (const float*)d_in[4];  const float* bu2 = (const float*)d_in[5];
    const float* Wr1 = (const float*)d_in[6];  const float* br1 = (const float*)d_in[7];
    const float* Wr2 = (const float*)d_in[8];  const float* br2 = (const float*)d_in[9];
    const float* Wn1 = (const float*)d_in[10]; const float* bn1 = (const float*)d_in[11];
    const float* Wn2 = (const float*)d_in[12]; const float* bn2 = (const float*)d_in[13];
    const float* Wo1 = (const float*)d_in[14]; const float* bo1 = (const float*)d_in[15];
    const float* Wo2 = (const float*)d_in[16]; const float* bo2 = (const float*)d_in[17];
    const float* Wd  = (const float*)d_in[18]; const float* bd  = (const float*)d_in[19];
    float* out = (float*)d_out;

    lobrm_fused<<<dim3(256), dim3(512), 0, stream>>>(
        data, tsteps, Wu1, bu1, Wu2, bu2, Wr1, br1, Wr2, br2,
        Wn1, bn1, Wn2, bn2, Wo1, bo1, Wo2, bo2, Wd, bd, out);
}

// Round 4
// 687.404 us; speedup vs baseline: 2.3119x; 1.1435x over previous
//
#include <hip/hip_runtime.h>

// LOBRM fused recurrence on gfx950 — fp16 hi/lo split-precision MFMA, R12.
// R12 = algebraic DAG flattening of R8. R9/R10/R11 proved the topology wall:
// 256 chains on 256 CUs, and every scheme to raise occupancy (M-split=2x work,
// natural co-residency=register wall, K-split=+6 barriers in lockstep) LOSES.
// Only lever: shorten the single-chain serial path. Fold mm2 through mm3 via
// precomputed fused weights (pre-kernel into d_ws):
//   Wo2u = Wo2 @ Wu1[0:64], Wo2r = Wo2 @ Wr1[0:64],
//   bu1' = bu1 + bo2@Wu1[0:64], br1' = br1 + bo2@Wr1[0:64]
// so hu = tanh(y@Wu1_y + feat@Wu1_f + z@Wo2u + bu1'), z = tanh(y@Wo1+bo1).
// New 5-level DAG (was 6 segments):
//   L0 (y,feat only): z-pre, U0=y@Wu1_y+feat@Wu1_f, R0, N0=feat@Wn1_f, vol
//       -> 38 indep MFMAs fill the post-barrier latency window
//   L1 (z): y1 (REGISTERS, no LDS trip), hu, hr     L2: u, r, cc=y1*r
//   L3 (cc): hn = tanh(cc@Wn1_y + N0)  [K 128->64]  L4: ns, blend, y, feat
// 5 barriers/step (was 6), K=128 segments gone, feat commit at step end.
// Grid 256, block 256 (4 waves), launch_bounds(256,1) — occupancy is
// structurally 1 wave/SIMD; registers may go ~330-350 (spill point ~450).
//  - feat loads for step i+1 issued at L0, committed at L4 (no rotation)
//  - stale feat rows harmless: gates discarded when upd=0 (ap flag)
//  - vol = hh term only (leaf output, error ~0.03 << 0.705)
//  - sT aliased for hn (z: L0->L1, hn: L3->L4; disjoint)

typedef __attribute__((ext_vector_type(8))) _Float16 half8;  // 8 fp16 = 4 VGPRs
typedef __attribute__((ext_vector_type(4))) float floatx4;   // MFMA C/D

#define MFMA(a, b, c) __builtin_amdgcn_mfma_f32_16x16x32_f16((a), (b), (c), 0, 0, 0)

__device__ __forceinline__ float tanhf_fast(float x) {
    float e = __builtin_exp2f(x * 2.8853900817779268f);  // e^{2x}
    return 1.0f - 2.0f / (e + 1.0f);                     // inf-safe: ->1 / -1
}
__device__ __forceinline__ float sigmoidf_fast(float x) {
    float e = __builtin_exp2f(x * -1.4426950408889634f); // e^{-x}
    return 1.0f / (1.0f + e);
}

struct W2 { half8 h, l; };

// ---- pre-pass: fused weight Wo2x = Wo2 @ WX1[0:64,:] (exact fp32),
//      fused bias bX1p = bX1 + bo2 @ WX1[0:64,:] ----
__global__ __launch_bounds__(256)
void lobrm_prep(const float* __restrict__ Wo2, const float* __restrict__ WX1,
                const float* __restrict__ bX1, const float* __restrict__ bo2,
                float* __restrict__ outW, float* __restrict__ outB)
{
    __shared__ float sA[4096], sB[4096];
    const int tid = threadIdx.x;
    for (int x = tid; x < 4096; x += 256) { sA[x] = Wo2[x]; sB[x] = WX1[x]; }
    __syncthreads();
    const int k = tid >> 2, n0 = (tid & 3) * 16;
    for (int c = 0; c < 16; ++c) {
        int n = n0 + c;
        float acc = 0.f;
#pragma unroll 8
        for (int j = 0; j < 64; ++j) acc += sA[k * 64 + j] * sB[j * 64 + n];
        outW[k * 64 + n] = acc;
    }
    if (tid < 64) {
        float acc = bX1[tid];
#pragma unroll 8
        for (int j = 0; j < 64; ++j) acc += bo2[j] * sB[j * 64 + tid];
        outB[tid] = acc;
    }
}

__global__ __launch_bounds__(256, 1)
void lobrm_fused(const float* __restrict__ data,   // (4096,64,100)
                 const int*   __restrict__ tsteps, // (4096,64)
                 const float* __restrict__ Wu1, const float* __restrict__ bu1,
                 const float* __restrict__ Wu2, const float* __restrict__ bu2,
                 const float* __restrict__ Wr1, const float* __restrict__ br1,
                 const float* __restrict__ Wr2, const float* __restrict__ br2,
                 const float* __restrict__ Wn1, const float* __restrict__ bn1,
                 const float* __restrict__ Wn2, const float* __restrict__ bn2,
                 const float* __restrict__ Wo1, const float* __restrict__ bo1,
                 const float* __restrict__ Wo2, const float* __restrict__ bo2,
                 const float* __restrict__ Wd,  const float* __restrict__ bd,
                 const float* __restrict__ ws,  // [Wo2u 4096 | Wo2r 4096 | bu1p 64 | br1p 64]
                 float* __restrict__ out)
{
    // fp16 hi/lo activation buffers, row stride 72 halfs (16B-aligned rows).
    // sT doubles as hn buffer (z: L0->L1, hn: L3->L4; disjoint lifetimes).
    __shared__ __align__(16) _Float16 sYh [16 * 72], sYl [16 * 72]; // y state
    __shared__ __align__(16) _Float16 sFh [16 * 72], sFl [16 * 72]; // feat (cols 50..63 = 0)
    __shared__ __align__(16) _Float16 sTh [16 * 72], sTl [16 * 72]; // z / hn
    __shared__ __align__(16) _Float16 sHuh[16 * 72], sHul[16 * 72];
    __shared__ __align__(16) _Float16 sHrh[16 * 72], sHrl[16 * 72];
    __shared__ __align__(16) _Float16 sCCh[16 * 72], sCCl[16 * 72]; // y1*r (64 cols only!)
    __shared__ float    sVol[16 * 132];   // vol per row per step
    __shared__ unsigned sFlg[2][16];      // apply = upd && m, double-buffered by step parity

    const int tid   = threadIdx.x;
    const int lane  = tid & 63;
    const int wv    = tid >> 6;          // wave = N-slice 0..3
    const int col16 = lane & 15;
    const int quad  = lane >> 4;
    const int ncol  = wv * 16 + col16;   // output column 0..63
    const int rowBase = blockIdx.x * 16;

    // ---- prologue: zero y + feat (pads must stay 0 forever) ----
    for (int x = tid; x < 16 * 72; x += 256) {
        sYh[x] = (_Float16)0.f; sYl[x] = (_Float16)0.f;
        sFh[x] = (_Float16)0.f; sFl[x] = (_Float16)0.f;
    }
    const float bdv = bd[0];

    // ---- weight hi/lo B-fragments (this wave's 16-col slice) ----
    // B-frag: lane holds B[(rowOff + kbg*32 + quad*8 + j)][n = ncol]
    auto loadW = [&](const float* W, int rowOff, int Kw, int kbg) -> W2 {
        W2 f;
#pragma unroll
        for (int j = 0; j < 8; ++j) {
            int k = kbg * 32 + quad * 8 + j;
            float v = (k < Kw) ? W[(rowOff + k) * 64 + ncol] : 0.0f;
            _Float16 h = (_Float16)v;
            f.h[j] = h;
            f.l[j] = (_Float16)(v - (float)h);
        }
        return f;
    };
    W2 wO1[2], wO2[2], wO2u[2], wO2r[2], wU2[2], wR2[2], wN2[2];
    W2 wU1y[2], wU1f[2], wR1y[2], wR1f[2], wN1y[2], wN1f[2];
#pragma unroll
    for (int t = 0; t < 2; ++t) {
        wO1[t]  = loadW(Wo1, 0, 64, t);
        wO2[t]  = loadW(Wo2, 0, 64, t);
        wO2u[t] = loadW(ws,        0, 64, t);   // fused Wo2@Wu1_y
        wO2r[t] = loadW(ws + 4096, 0, 64, t);   // fused Wo2@Wr1_y
        wU2[t]  = loadW(Wu2, 0, 64, t);
        wR2[t]  = loadW(Wr2, 0, 64, t);
        wN2[t]  = loadW(Wn2, 0, 64, t);
        wU1y[t] = loadW(Wu1, 0, 64, t);
        wU1f[t] = loadW(Wu1, 64, 50, t);        // feat rows 64..113
        wR1y[t] = loadW(Wr1, 0, 64, t);
        wR1f[t] = loadW(Wr1, 64, 50, t);
        wN1y[t] = loadW(Wn1, 0, 64, t);
        wN1f[t] = loadW(Wn1, 64, 50, t);
    }
    // vol B-frag (wave 0 only): column 0 = Wd, cols 1..15 = 0; hi-only (leaf).
    half8 vwd[2];
#pragma unroll
    for (int kb = 0; kb < 2; ++kb)
#pragma unroll
        for (int j = 0; j < 8; ++j) {
            int k = kb * 32 + quad * 8 + j;
            vwd[kb][j] = (_Float16)((col16 == 0) ? Wd[k] : 0.0f);
        }
    const float bo1v = bo1[ncol], bo2v = bo2[ncol];
    const float bu2v = bu2[ncol], br2v = br2[ncol];
    const float bn1v = bn1[ncol], bn2v = bn2[ncol];
    const float bu1pv = ws[8192 + ncol];        // bu1 + bo2@Wu1_y
    const float br1pv = ws[8256 + ncol];        // br1 + bo2@Wr1_y

    // ---- presence masks: wave wv owns rows 4wv..4wv+3 for feat loading ----
    unsigned long long mLo[4], mHi[4];
    const float* dPtr[4];
#pragma unroll
    for (int r4 = 0; r4 < 4; ++r4) {
        int b = rowBase + 4 * wv + r4;
        int v = tsteps[b * 64 + lane];
        unsigned long long lo = (v < 64) ? (1ull << v) : 0ull;
        unsigned long long hi = (v >= 64) ? (1ull << (v - 64)) : 0ull;
#pragma unroll
        for (int st = 1; st < 64; st <<= 1) {
            lo |= __shfl_xor(lo, st);
            hi |= __shfl_xor(hi, st);
        }
        mLo[r4] = lo; mHi[r4] = hi;
        dPtr[r4] = data + (size_t)b * 6400;
    }

    // ---- step-0 feat: load + commit now (consumed at L0 of step 0) ----
#pragma unroll
    for (int r4 = 0; r4 < 4; ++r4) {
        int row = 4 * wv + r4;
        bool h0 = (mLo[r4] & 1ull) != 0ull;
        float f0 = 0.f, m0 = 0.f;
        if (h0) {
            const float* dp = dPtr[r4];
            dPtr[r4] = dp + 100;
            if (lane < 50) { f0 = dp[lane]; m0 = dp[50 + lane]; }
            if (lane < 50) {
                _Float16 h = (_Float16)f0;
                sFh[row * 72 + lane] = h;
                sFl[row * 72 + lane] = (_Float16)(f0 - (float)h);
            }
            unsigned long long bal = __ballot(m0 > 0.f);
            if (lane == 0) sFlg[0][row] = bal ? 1u : 0u;
        } else if (lane == 0) {
            sFlg[0][row] = 0u;
        }
    }
    __syncthreads();

    floatx4 pc = {0.f, 0.f, 0.f, 0.f};   // fp32 y state, C-layout slice
    const floatx4 z4 = {0.f, 0.f, 0.f, 0.f};

    const int aOff = col16 * 72 + quad * 8;    // A-frag base (stride 72)

    for (int i = 0; i < 128; ++i) {
        // ================= L0: needs only y + feat =================
        // z-pre = y@Wo1+bo1; U0 = y@Wu1_y+feat@Wu1_f+bu1'; R0; N0; vol.
        floatx4 U0, R0, N0, y1, uG;
        {
            half8 yh0 = *(const half8*)&sYh[aOff];
            half8 yh1 = *(const half8*)&sYh[aOff + 32];
            half8 yl0 = *(const half8*)&sYl[aOff];
            half8 yl1 = *(const half8*)&sYl[aOff + 32];
            half8 fh0 = *(const half8*)&sFh[aOff];
            half8 fh1 = *(const half8*)&sFh[aOff + 32];
            half8 fl0 = *(const half8*)&sFl[aOff];
            half8 fl1 = *(const half8*)&sFl[aOff + 32];
            // z chains
            floatx4 zc = {bo1v, bo1v, bo1v, bo1v};
            floatx4 zhh = MFMA(yh1, wO1[1].h, MFMA(yh0, wO1[0].h, zc));
            floatx4 zhl = MFMA(yh1, wO1[1].l, MFMA(yh0, wO1[0].l, z4));
            floatx4 zlh = MFMA(yl1, wO1[1].h, MFMA(yl0, wO1[0].h, z4));
            // vol (wave 0, hi-only)
            if (wv == 0) {
                floatx4 v = MFMA(yh1, vwd[1], MFMA(yh0, vwd[0], z4));
                if (col16 == 0) {
#pragma unroll
                    for (int r = 0; r < 4; ++r)
                        sVol[(quad * 4 + r) * 132 + i] = v[r] + bdv;
                }
            }
            // U0 (y-part + feat-part chained into one accumulator)
            floatx4 cu = {bu1pv, bu1pv, bu1pv, bu1pv};
            floatx4 uhh = MFMA(fh1, wU1f[1].h, MFMA(fh0, wU1f[0].h,
                          MFMA(yh1, wU1y[1].h, MFMA(yh0, wU1y[0].h, cu))));
            floatx4 uhl = MFMA(fh1, wU1f[1].l, MFMA(fh0, wU1f[0].l,
                          MFMA(yh1, wU1y[1].l, MFMA(yh0, wU1y[0].l, z4))));
            floatx4 ulh = MFMA(fl1, wU1f[1].h, MFMA(fl0, wU1f[0].h,
                          MFMA(yl1, wU1y[1].h, MFMA(yl0, wU1y[0].h, z4))));
            U0 = uhh + (uhl + ulh);
            // R0
            floatx4 cr = {br1pv, br1pv, br1pv, br1pv};
            floatx4 rhh = MFMA(fh1, wR1f[1].h, MFMA(fh0, wR1f[0].h,
                          MFMA(yh1, wR1y[1].h, MFMA(yh0, wR1y[0].h, cr))));
            floatx4 rhl = MFMA(fh1, wR1f[1].l, MFMA(fh0, wR1f[0].l,
                          MFMA(yh1, wR1y[1].l, MFMA(yh0, wR1y[0].l, z4))));
            floatx4 rlh = MFMA(fl1, wR1f[1].h, MFMA(fl0, wR1f[0].h,
                          MFMA(yl1, wR1y[1].h, MFMA(yl0, wR1y[0].h, z4))));
            R0 = rhh + (rhl + rlh);
            // N0 = feat@Wn1_f + bn1
            floatx4 cn = {bn1v, bn1v, bn1v, bn1v};
            floatx4 nhh = MFMA(fh1, wN1f[1].h, MFMA(fh0, wN1f[0].h, cn));
            floatx4 nhl = MFMA(fh1, wN1f[1].l, MFMA(fh0, wN1f[0].l, z4));
            floatx4 nlh = MFMA(fl1, wN1f[1].h, MFMA(fl0, wN1f[0].h, z4));
            N0 = nhh + (nhl + nlh);
            // finalize z -> sT
            floatx4 zacc = zhh + (zhl + zlh);
#pragma unroll
            for (int r = 0; r < 4; ++r) {
                float t = tanhf_fast(zacc[r]);
                _Float16 h = (_Float16)t;
                int idx = (quad * 4 + r) * 72 + ncol;
                sTh[idx] = h;
                sTl[idx] = (_Float16)(t - (float)h);
            }
        }
        // issue NEXT step's feat loads (land under L0->B1; committed at L4)
        const int ip = i + 1;
        bool hasN[4];
        float fN[4], mN[4];
#pragma unroll
        for (int r4 = 0; r4 < 4; ++r4) {
            unsigned long long mm =
                (ip < 64) ? (mLo[r4] >> ip)
                          : ((ip < 128) ? (mHi[r4] >> (ip - 64)) : 0ull);
            hasN[r4] = (mm & 1ull) != 0ull;
            fN[r4] = 0.f; mN[r4] = 0.f;
            if (hasN[r4]) {
                const float* dp = dPtr[r4];
                dPtr[r4] = dp + 100;
                if (lane < 50) { fN[r4] = dp[lane]; mN[r4] = dp[50 + lane]; }
            }
        }
        __syncthreads();                                   // B1 (z published)

        // ================= L1: needs z =================
        // y1 = pc + z@Wo2 + bo2 (registers); hu = tanh(U0 + z@Wo2u); hr.
        {
            half8 th0 = *(const half8*)&sTh[aOff];
            half8 th1 = *(const half8*)&sTh[aOff + 32];
            half8 tl0 = *(const half8*)&sTl[aOff];
            half8 tl1 = *(const half8*)&sTl[aOff + 32];
            floatx4 cb = {bo2v, bo2v, bo2v, bo2v};
            floatx4 yhh = MFMA(th1, wO2[1].h, MFMA(th0, wO2[0].h, cb));
            floatx4 yhl = MFMA(th1, wO2[1].l, MFMA(th0, wO2[0].l, z4));
            floatx4 ylh = MFMA(tl1, wO2[1].h, MFMA(tl0, wO2[0].h, z4));
            floatx4 yacc = yhh + (yhl + ylh);
            floatx4 uhh = MFMA(th1, wO2u[1].h, MFMA(th0, wO2u[0].h, U0));
            floatx4 uhl = MFMA(th1, wO2u[1].l, MFMA(th0, wO2u[0].l, z4));
            floatx4 ulh = MFMA(tl1, wO2u[1].h, MFMA(tl0, wO2u[0].h, z4));
            floatx4 hua = uhh + (uhl + ulh);
            floatx4 rhh = MFMA(th1, wO2r[1].h, MFMA(th0, wO2r[0].h, R0));
            floatx4 rhl = MFMA(th1, wO2r[1].l, MFMA(th0, wO2r[0].l, z4));
            floatx4 rlh = MFMA(tl1, wO2r[1].h, MFMA(tl0, wO2r[0].h, z4));
            floatx4 hra = rhh + (rhl + rlh);
#pragma unroll
            for (int r = 0; r < 4; ++r) {
                y1[r] = pc[r] + yacc[r];
                float tu = tanhf_fast(hua[r]);
                float tr = tanhf_fast(hra[r]);
                int idx = (quad * 4 + r) * 72 + ncol;
                _Float16 hu = (_Float16)tu, hr = (_Float16)tr;
                sHuh[idx] = hu; sHul[idx] = (_Float16)(tu - (float)hu);
                sHrh[idx] = hr; sHrl[idx] = (_Float16)(tr - (float)hr);
            }
        }
        __syncthreads();                                   // B2 (hu, hr published)

        // ================= L2: u = sig(hu@Wu2+bu2), r = sig(hr@Wr2+br2) ====
        {
            half8 u0h = *(const half8*)&sHuh[aOff];
            half8 u0l = *(const half8*)&sHul[aOff];
            half8 u1h = *(const half8*)&sHuh[aOff + 32];
            half8 u1l = *(const half8*)&sHul[aOff + 32];
            floatx4 cu = {bu2v, bu2v, bu2v, bu2v};
            floatx4 au = MFMA(u1h, wU2[1].h, MFMA(u0h, wU2[0].h, cu))
                       + (MFMA(u1h, wU2[1].l, MFMA(u0h, wU2[0].l, z4))
                        + MFMA(u1l, wU2[1].h, MFMA(u0l, wU2[0].h, z4)));
            half8 r0h = *(const half8*)&sHrh[aOff];
            half8 r0l = *(const half8*)&sHrl[aOff];
            half8 r1h = *(const half8*)&sHrh[aOff + 32];
            half8 r1l = *(const half8*)&sHrl[aOff + 32];
            floatx4 cr = {br2v, br2v, br2v, br2v};
            floatx4 ar = MFMA(r1h, wR2[1].h, MFMA(r0h, wR2[0].h, cr))
                       + (MFMA(r1h, wR2[1].l, MFMA(r0h, wR2[0].l, z4))
                        + MFMA(r1l, wR2[1].h, MFMA(r0l, wR2[0].h, z4)));
#pragma unroll
            for (int r = 0; r < 4; ++r) {
                uG[r] = sigmoidf_fast(au[r]);
                float rg = sigmoidf_fast(ar[r]);
                float cc = y1[r] * rg;
                _Float16 h = (_Float16)cc;
                int idx = (quad * 4 + r) * 72 + ncol;
                sCCh[idx] = h;
                sCCl[idx] = (_Float16)(cc - (float)h);
            }
        }
        __syncthreads();                                   // B3 (cc published)

        // ================= L3: hn = tanh(cc@Wn1_y + N0) -> sT alias ========
        {
            half8 ch0 = *(const half8*)&sCCh[aOff];
            half8 ch1 = *(const half8*)&sCCh[aOff + 32];
            half8 cl0 = *(const half8*)&sCCl[aOff];
            half8 cl1 = *(const half8*)&sCCl[aOff + 32];
            floatx4 nhh = MFMA(ch1, wN1y[1].h, MFMA(ch0, wN1y[0].h, N0));
            floatx4 nhl = MFMA(ch1, wN1y[1].l, MFMA(ch0, wN1y[0].l, z4));
            floatx4 nlh = MFMA(cl1, wN1y[1].h, MFMA(cl0, wN1y[0].h, z4));
            floatx4 hna = nhh + (nhl + nlh);
#pragma unroll
            for (int r = 0; r < 4; ++r) {
                float t = tanhf_fast(hna[r]);
                _Float16 h = (_Float16)t;
                int idx = (quad * 4 + r) * 72 + ncol;
                sTh[idx] = h;
                sTl[idx] = (_Float16)(t - (float)h);
            }
        }
        __syncthreads();                                   // B4 (hn published)

        // ================= L4: ns = hn@Wn2+bn2; blend; y; feat commit ======
        {
            half8 n0h = *(const half8*)&sTh[aOff];
            half8 n0l = *(const half8*)&sTl[aOff];
            half8 n1h = *(const half8*)&sTh[aOff + 32];
            half8 n1l = *(const half8*)&sTl[aOff + 32];
            floatx4 cn = {bn2v, bn2v, bn2v, bn2v};
            floatx4 acc = MFMA(n1h, wN2[1].h, MFMA(n0h, wN2[0].h, cn))
                        + (MFMA(n1h, wN2[1].l, MFMA(n0h, wN2[0].l, z4))
                         + MFMA(n1l, wN2[1].h, MFMA(n0l, wN2[0].h, z4)));
#pragma unroll
            for (int r = 0; r < 4; ++r) {
                float ns = acc[r];
                float ny = (1.0f - uG[r]) * ns + uG[r] * y1[r];
                unsigned ap = sFlg[i & 1][quad * 4 + r];   // upd && m
                float nY = ap ? ny : y1[r];                // select: NaN-safe
                pc[r] = nY;
                int idx = (quad * 4 + r) * 72 + ncol;
                _Float16 h = (_Float16)nY;
                sYh[idx] = h;
                sYl[idx] = (_Float16)(nY - (float)h);
            }
            // feat commit for step i+1 (loads issued at L0, long landed)
#pragma unroll
            for (int r4 = 0; r4 < 4; ++r4) {
                int row = 4 * wv + r4;
                if (hasN[r4]) {
                    if (lane < 50) {
                        float f = fN[r4];
                        _Float16 h = (_Float16)f;
                        sFh[row * 72 + lane] = h;
                        sFl[row * 72 + lane] = (_Float16)(f - (float)h);
                    }
                    unsigned long long bal = __ballot(mN[r4] > 0.f);
                    if (lane == 0) sFlg[(i + 1) & 1][row] = bal ? 1u : 0u;
                } else if (lane == 0) {
                    sFlg[(i + 1) & 1][row] = 0u;
                }
            }
        }
        __syncthreads();                                   // B5 (y + feat published)
    }

    // ---- epilogue ----
#pragma unroll
    for (int r = 0; r < 4; ++r) {
        int b = rowBase + quad * 4 + r;
        out[(size_t)b * 64 + ncol] = pc[r];
    }
    float* out1 = out + (size_t)4096 * 64;
    float* out2 = out1 + (size_t)4096 * 63;
#pragma unroll
    for (int r4 = 0; r4 < 4; ++r4) {
        int row = 4 * wv + r4;
        int b = rowBase + row;
        if (lane < 63) {
            int t0 = tsteps[b * 64 + lane];
            int t1 = tsteps[b * 64 + lane + 1];
            int iv = t0 < 126 ? t0 : 126;
            out1[(size_t)b * 63 + lane] = sVol[row * 132 + iv + 1];
            out2[(size_t)b * 63 + lane] = (float)(t1 - t0);
        }
    }
}

extern "C" void kernel_launch(void* const* d_in, const int* in_sizes, int n_in,
                              void* d_out, int out_size, void* d_ws, size_t ws_size,
                              hipStream_t stream) {
    const float* data   = (const float*)d_in[0];
    const int*   tsteps = (const int*)  d_in[1];
    const float* Wu1 = (const float*)d_in[2];  const float* bu1 = (const float*)d_in[3];
    const float* Wu2 = (const float*)d_in[4];  const float* bu2 = (const float*)d_in[5];
    const float* Wr1 = (const float*)d_in[6];  const float* br1 = (const float*)d_in[7];
    const float* Wr2 = (const float*)d_in[8];  const float* br2 = (const float*)d_in[9];
    const float* Wn1 = (const float*)d_in[10]; const float* bn1 = (const float*)d_in[11];
    const float* Wn2 = (const float*)d_in[12]; const float* bn2 = (const float*)d_in[13];
    const float* Wo1 = (const float*)d_in[14]; const float* bo1 = (const float*)d_in[15];
    const float* Wo2 = (const float*)d_in[16]; const float* bo2 = (const float*)d_in[17];
    const float* Wd  = (const float*)d_in[18]; const float* bd  = (const float*)d_in[19];
    float* out = (float*)d_out;
    float* ws  = (float*)d_ws;

    // fused weights/biases into workspace (stream-ordered before main kernel)
    lobrm_prep<<<dim3(1), dim3(256), 0, stream>>>(Wo2, Wu1, bu1, bo2, ws, ws + 8192);
    lobrm_prep<<<dim3(1), dim3(256), 0, stream>>>(Wo2, Wr1, br1, bo2, ws + 4096, ws + 8192 + 64);

    lobrm_fused<<<dim3(256), dim3(256), 0, stream>>>(
        data, tsteps, Wu1, bu1, Wu2, bu2, Wr1, br1, Wr2, br2,
        Wn1, bn1, Wn2, bn2, Wo1, bo1, Wo2, bo2, Wd, bd, ws, out);
}

// Round 7
// 608.583 us; speedup vs baseline: 2.6113x; 1.1295x over previous
//
#include <hip/hip_runtime.h>

// LOBRM fused recurrence on gfx950 — R15: R8 numerics + latency-only shaves.
// R13/R14 proved the precision floor: gate-lo (absmax 6.6) and weight-lo
// (22.7) are BOTH load-bearing — the recurrence amplifies per-step noise
// ~1.08x/step, so only R8's full hi/lo scheme passes. R9-R12 killed the
// occupancy and algebra levers. Remaining slack: __syncthreads() emits
// s_waitcnt vmcnt(0) before every s_barrier, draining the 8 feat global
// loads cold at B1 every step (~100-500 cyc exposed; R8's own comment
// flags this). R15 changes ONLY scheduling:
//  1. raw lgkm-only barriers (m201-proven pattern) — feat loads float
//     across barriers, counted vmcnt wait lands at use (next iter's C)
//  2. sFlg read hoisted to one broadcast b128 right after B2 (was 4 b32
//     on mm6's critical tail)
//  3. vol MFMAs moved from mm1 (B1-critical) to mm4 (shortest segment;
//     sYh stable until mm6's writes)
// Everything else — every MFMA, cvt, store, flag — bit-identical to R8.

typedef __attribute__((ext_vector_type(8))) _Float16 half8;  // 8 fp16 = 4 VGPRs
typedef __attribute__((ext_vector_type(4))) float floatx4;   // MFMA C/D
typedef __attribute__((ext_vector_type(4))) unsigned uint4v;

#define MFMA(a, b, c) __builtin_amdgcn_mfma_f32_16x16x32_f16((a), (b), (c), 0, 0, 0)

__device__ __forceinline__ float tanhf_fast(float x) {
    float e = __builtin_exp2f(x * 2.8853900817779268f);  // e^{2x}
    return 1.0f - 2.0f / (e + 1.0f);                     // inf-safe: ->1 / -1
}
__device__ __forceinline__ float sigmoidf_fast(float x) {
    float e = __builtin_exp2f(x * -1.4426950408889634f); // e^{-x}
    return 1.0f / (1.0f + e);
}

// lgkm-only barrier: LDS producer->consumer ordering WITHOUT the vmcnt(0)
// drain __syncthreads() forces. Pattern verified in the 8-phase template
// (learn_hip m201): asm waitcnt + raw s_barrier; memory clobbers + sched
// fence stop compiler motion of LDS ops across it.
__device__ __forceinline__ void bar_lgkm() {
    asm volatile("s_waitcnt lgkmcnt(0)" ::: "memory");
    __builtin_amdgcn_s_barrier();
    asm volatile("" ::: "memory");
    __builtin_amdgcn_sched_barrier(0);
}

struct W2 { half8 h, l; };

__global__ __launch_bounds__(256, 1)
void lobrm_fused(const float* __restrict__ data,   // (4096,64,100)
                 const int*   __restrict__ tsteps, // (4096,64)
                 const float* __restrict__ Wu1, const float* __restrict__ bu1,
                 const float* __restrict__ Wu2, const float* __restrict__ bu2,
                 const float* __restrict__ Wr1, const float* __restrict__ br1,
                 const float* __restrict__ Wr2, const float* __restrict__ br2,
                 const float* __restrict__ Wn1, const float* __restrict__ bn1,
                 const float* __restrict__ Wn2, const float* __restrict__ bn2,
                 const float* __restrict__ Wo1, const float* __restrict__ bo1,
                 const float* __restrict__ Wo2, const float* __restrict__ bo2,
                 const float* __restrict__ Wd,  const float* __restrict__ bd,
                 float* __restrict__ out)
{
    // fp16 hi/lo activation buffers. Row strides 72/136 halfs: 16B-aligned.
    // sTh/sTl double as Hn buffers (T: mm1->mm2, Hn: mm5->mm6; disjoint).
    __shared__ __align__(16) _Float16 sYh [16 * 72],  sYl [16 * 72];
    __shared__ __align__(16) _Float16 sTh [16 * 72],  sTl [16 * 72];
    __shared__ __align__(16) _Float16 sHuh[16 * 72],  sHul[16 * 72];
    __shared__ __align__(16) _Float16 sHrh[16 * 72],  sHrl[16 * 72];
    __shared__ __align__(16) _Float16 sYCh[16 * 136], sYCl[16 * 136]; // [y1|feat|0]
    __shared__ __align__(16) _Float16 sCCh[16 * 136], sCCl[16 * 136]; // [y1*r|feat|0]
    __shared__ float    sVol[16 * 132];   // vol per row per step
    __shared__ __align__(16) unsigned sFlg[16];  // apply = upd && m, per row

    const int tid   = threadIdx.x;
    const int lane  = tid & 63;
    const int wv    = tid >> 6;          // wave = N-slice
    const int col16 = lane & 15;
    const int quad  = lane >> 4;
    const int ncol  = wv * 16 + col16;   // output column 0..63
    const int rowBase = blockIdx.x * 16;

    // ---- prologue: zero state + pad regions (pads must stay 0 forever) ----
    for (int x = tid; x < 16 * 72; x += 256) {
        sYh[x] = (_Float16)0.f; sYl[x] = (_Float16)0.f;
    }
    for (int x = tid; x < 16 * 136; x += 256) {
        sYCh[x] = (_Float16)0.f; sYCl[x] = (_Float16)0.f;
        sCCh[x] = (_Float16)0.f; sCCl[x] = (_Float16)0.f;
    }
    const float bdv = bd[0];

    // ---- weight hi/lo B-fragments (this wave's 16-col slice) ----
    // B-frag for 16x16x32: lane holds B[k = kb*32 + quad*8 + j][n = ncol]
    auto loadW = [&](const float* W, int Kw, int kb) -> W2 {
        W2 f;
#pragma unroll
        for (int j = 0; j < 8; ++j) {
            int k = kb * 32 + quad * 8 + j;
            float v = (k < Kw) ? W[k * 64 + ncol] : 0.0f;
            _Float16 h = (_Float16)v;
            f.h[j] = h;
            f.l[j] = (_Float16)(v - (float)h);
        }
        return f;
    };
    W2 wO1[2], wO2[2], wU2[2], wR2[2], wN2[2], wU1[4], wR1[4], wN1[4];
#pragma unroll
    for (int kb = 0; kb < 2; ++kb) {
        wO1[kb] = loadW(Wo1, 64, kb);
        wO2[kb] = loadW(Wo2, 64, kb);
        wU2[kb] = loadW(Wu2, 64, kb);
        wR2[kb] = loadW(Wr2, 64, kb);
        wN2[kb] = loadW(Wn2, 64, kb);
    }
#pragma unroll
    for (int kb = 0; kb < 4; ++kb) {
        wU1[kb] = loadW(Wu1, 114, kb);
        wR1[kb] = loadW(Wr1, 114, kb);
        wN1[kb] = loadW(Wn1, 114, kb);
    }
    // vol B-frag (only wave 0 uses it): column 0 = Wd, cols 1..15 = 0.
    // hi-only: vol is a leaf output, lo terms contribute ~0.03 << 0.705.
    half8 vwd[2];
#pragma unroll
    for (int kb = 0; kb < 2; ++kb)
#pragma unroll
        for (int j = 0; j < 8; ++j) {
            int k = kb * 32 + quad * 8 + j;
            vwd[kb][j] = (_Float16)((col16 == 0) ? Wd[k] : 0.0f);
        }
    const float bo1v = bo1[ncol], bo2v = bo2[ncol];
    const float bu1v = bu1[ncol], bu2v = bu2[ncol];
    const float br1v = br1[ncol], br2v = br2[ncol];
    const float bn1v = bn1[ncol], bn2v = bn2[ncol];

    // ---- presence masks (dedup == reference's presence): wave wv owns
    // rows 4wv..4wv+3 for feat loading ----
    unsigned long long mLo[4], mHi[4];
    const float* dPtr[4];
#pragma unroll
    for (int r4 = 0; r4 < 4; ++r4) {
        int b = rowBase + 4 * wv + r4;
        int v = tsteps[b * 64 + lane];
        unsigned long long lo = (v < 64) ? (1ull << v) : 0ull;
        unsigned long long hi = (v >= 64) ? (1ull << (v - 64)) : 0ull;
#pragma unroll
        for (int st = 1; st < 64; st <<= 1) {
            lo |= __shfl_xor(lo, st);
            hi |= __shfl_xor(hi, st);
        }
        mLo[r4] = lo; mHi[r4] = hi;
        dPtr[r4] = data + (size_t)b * 6400;
    }
    __syncthreads();   // one-time init barrier (full drain is fine here)

    floatx4 pc = {0.f, 0.f, 0.f, 0.f};   // fp32 state, C-layout slice
    const floatx4 z = {0.f, 0.f, 0.f, 0.f};

    const int aOff  = col16 * 72 + quad * 8;   // stride-72 A-frag base
    const int aOffH = col16 * 136 + quad * 8;  // stride-136 A-frag base

    // ---- prefetch step 0's feat loads ----
    bool hasU[4];
    float fv[4], mv[4];
#pragma unroll
    for (int r4 = 0; r4 < 4; ++r4) {
        hasU[r4] = (mLo[r4] & 1ull) != 0ull;
        fv[r4] = 0.f; mv[r4] = 0.f;
        if (hasU[r4]) {
            const float* dp = dPtr[r4];
            dPtr[r4] = dp + 100;
            if (lane < 50) { fv[r4] = dp[lane]; mv[r4] = dp[50 + lane]; }
        }
    }

    for (int i = 0; i < 128; ++i) {
        // ---- A) issue NEXT step's feat loads (consumed next iteration at C;
        //      with lgkm-only barriers they float across B1..B6 and the
        //      counted vmcnt wait lands at their use, a full step later) ----
        const int ip = i + 1;
        bool hasN[4];
        float fN[4], mN[4];
#pragma unroll
        for (int r4 = 0; r4 < 4; ++r4) {
            unsigned long long mm =
                (ip < 64) ? (mLo[r4] >> ip)
                          : ((ip < 128) ? (mHi[r4] >> (ip - 64)) : 0ull);
            hasN[r4] = (mm & 1ull) != 0ull;
            fN[r4] = 0.f; mN[r4] = 0.f;
            if (hasN[r4]) {
                const float* dp = dPtr[r4];
                dPtr[r4] = dp + 100;
                if (lane < 50) { fN[r4] = dp[lane]; mN[r4] = dp[50 + lane]; }
            }
        }

        // ---- mm1: t = tanh(y @ Wo1 + bo1) ----
        {
            half8 a0h = *(const half8*)&sYh[aOff];
            half8 a0l = *(const half8*)&sYl[aOff];
            half8 a1h = *(const half8*)&sYh[aOff + 32];
            half8 a1l = *(const half8*)&sYl[aOff + 32];
            floatx4 cb = {bo1v, bo1v, bo1v, bo1v};
            floatx4 hh = MFMA(a1h, wO1[1].h, MFMA(a0h, wO1[0].h, cb));
            floatx4 hl = MFMA(a1h, wO1[1].l, MFMA(a0h, wO1[0].l, z));
            floatx4 lh = MFMA(a1l, wO1[1].h, MFMA(a0l, wO1[0].h, z));
            floatx4 acc = hh + (hl + lh);
#pragma unroll
            for (int r = 0; r < 4; ++r) {
                float t = tanhf_fast(acc[r]);
                _Float16 h = (_Float16)t;
                int idx = (quad * 4 + r) * 72 + ncol;
                sTh[idx] = h;
                sTl[idx] = (_Float16)(t - (float)h);
            }
        }
        bar_lgkm();                                        // B1

        // ---- mm2: y1 = y + t @ Wo2 + bo2 ----
        floatx4 y1;
        {
            half8 t0h = *(const half8*)&sTh[aOff];
            half8 t0l = *(const half8*)&sTl[aOff];
            half8 t1h = *(const half8*)&sTh[aOff + 32];
            half8 t1l = *(const half8*)&sTl[aOff + 32];
            floatx4 cb = {bo2v, bo2v, bo2v, bo2v};
            floatx4 hh = MFMA(t1h, wO2[1].h, MFMA(t0h, wO2[0].h, cb));
            floatx4 hl = MFMA(t1h, wO2[1].l, MFMA(t0h, wO2[0].l, z));
            floatx4 lh = MFMA(t1l, wO2[1].h, MFMA(t0l, wO2[0].h, z));
            floatx4 acc = hh + (hl + lh);
#pragma unroll
            for (int r = 0; r < 4; ++r) {
                y1[r] = pc[r] + acc[r];
                _Float16 h = (_Float16)y1[r];
                int idx = (quad * 4 + r) * 136 + ncol;
                sYCh[idx] = h;
                sYCl[idx] = (_Float16)(y1[r] - (float)h);
            }
        }

        // ---- C) feat commit (hi+lo, prefetched last iter) + ballot flags ----
#pragma unroll
        for (int r4 = 0; r4 < 4; ++r4) {
            int row = 4 * wv + r4;
            if (hasU[r4]) {
                if (lane < 50) {
                    float f = fv[r4];
                    _Float16 h = (_Float16)f;
                    _Float16 l = (_Float16)(f - (float)h);
                    int idx = row * 136 + 64 + lane;
                    sYCh[idx] = h; sYCl[idx] = l;
                    sCCh[idx] = h; sCCl[idx] = l;
                }
                unsigned long long bal = __ballot(mv[r4] > 0.f);
                if (lane == 0) sFlg[row] = bal ? 1u : 0u;
            } else if (lane == 0) {
                sFlg[row] = 0u;
            }
        }
        bar_lgkm();                                        // B2

        // sFlg hoist: one broadcast b128 read (same addr per quad-group),
        // latency hidden under mm3; mm6 consumes from registers.
        uint4v apV = *(const uint4v*)&sFlg[quad * 4];

        // ---- mm3: hu = tanh(yc@Wu1+bu1), hr = tanh(yc@Wr1+br1), K=128 ----
        {
            half8 ah0 = *(const half8*)&sYCh[aOffH];
            half8 ah1 = *(const half8*)&sYCh[aOffH + 32];
            half8 ah2 = *(const half8*)&sYCh[aOffH + 64];
            half8 ah3 = *(const half8*)&sYCh[aOffH + 96];
            half8 al0 = *(const half8*)&sYCl[aOffH];
            half8 al1 = *(const half8*)&sYCl[aOffH + 32];
            half8 al2 = *(const half8*)&sYCl[aOffH + 64];
            half8 al3 = *(const half8*)&sYCl[aOffH + 96];
            floatx4 cu = {bu1v, bu1v, bu1v, bu1v};
            floatx4 cr = {br1v, br1v, br1v, br1v};
            floatx4 uhh = MFMA(ah3, wU1[3].h, MFMA(ah2, wU1[2].h,
                          MFMA(ah1, wU1[1].h, MFMA(ah0, wU1[0].h, cu))));
            floatx4 uhl = MFMA(ah3, wU1[3].l, MFMA(ah2, wU1[2].l,
                          MFMA(ah1, wU1[1].l, MFMA(ah0, wU1[0].l, z))));
            floatx4 ulh = MFMA(al3, wU1[3].h, MFMA(al2, wU1[2].h,
                          MFMA(al1, wU1[1].h, MFMA(al0, wU1[0].h, z))));
            floatx4 rhh = MFMA(ah3, wR1[3].h, MFMA(ah2, wR1[2].h,
                          MFMA(ah1, wR1[1].h, MFMA(ah0, wR1[0].h, cr))));
            floatx4 rhl = MFMA(ah3, wR1[3].l, MFMA(ah2, wR1[2].l,
                          MFMA(ah1, wR1[1].l, MFMA(ah0, wR1[0].l, z))));
            floatx4 rlh = MFMA(al3, wR1[3].h, MFMA(al2, wR1[2].h,
                          MFMA(al1, wR1[1].h, MFMA(al0, wR1[0].h, z))));
            floatx4 aU = uhh + (uhl + ulh);
            floatx4 aR = rhh + (rhl + rlh);
#pragma unroll
            for (int r = 0; r < 4; ++r) {
                float tu = tanhf_fast(aU[r]);
                float tr = tanhf_fast(aR[r]);
                int idx = (quad * 4 + r) * 72 + ncol;
                _Float16 hu = (_Float16)tu, hr = (_Float16)tr;
                sHuh[idx] = hu; sHul[idx] = (_Float16)(tu - (float)hu);
                sHrh[idx] = hr; sHrl[idx] = (_Float16)(tr - (float)hr);
            }
        }
        bar_lgkm();                                        // B3

        // ---- mm4: u = sig(hu@Wu2+bu2), r = sig(hr@Wr2+br2); cc = y1*r;
        //      vol = y @ Wd + bd (moved here: shortest segment, sYh stable
        //      until mm6's writes; was on mm1's B1-critical path) ----
        floatx4 uG;
        {
            half8 u0h = *(const half8*)&sHuh[aOff];
            half8 u0l = *(const half8*)&sHul[aOff];
            half8 u1h = *(const half8*)&sHuh[aOff + 32];
            half8 u1l = *(const half8*)&sHul[aOff + 32];
            floatx4 cu = {bu2v, bu2v, bu2v, bu2v};
            floatx4 cr = {br2v, br2v, br2v, br2v};
            floatx4 au = MFMA(u1h, wU2[1].h, MFMA(u0h, wU2[0].h, cu))
                       + (MFMA(u1h, wU2[1].l, MFMA(u0h, wU2[0].l, z))
                        + MFMA(u1l, wU2[1].h, MFMA(u0l, wU2[0].h, z)));
            half8 r0h = *(const half8*)&sHrh[aOff];
            half8 r0l = *(const half8*)&sHrl[aOff];
            half8 r1h = *(const half8*)&sHrh[aOff + 32];
            half8 r1l = *(const half8*)&sHrl[aOff + 32];
            floatx4 ar = MFMA(r1h, wR2[1].h, MFMA(r0h, wR2[0].h, cr))
                       + (MFMA(r1h, wR2[1].l, MFMA(r0h, wR2[0].l, z))
                        + MFMA(r1l, wR2[1].h, MFMA(r0l, wR2[0].h, z)));
            if (wv == 0) {
                half8 a0h = *(const half8*)&sYh[aOff];
                half8 a1h = *(const half8*)&sYh[aOff + 32];
                floatx4 v = MFMA(a1h, vwd[1], MFMA(a0h, vwd[0], z));
                if (col16 == 0) {
#pragma unroll
                    for (int r = 0; r < 4; ++r)
                        sVol[(quad * 4 + r) * 132 + i] = v[r] + bdv;
                }
            }
#pragma unroll
            for (int r = 0; r < 4; ++r) {
                uG[r] = sigmoidf_fast(au[r]);
                float rg = sigmoidf_fast(ar[r]);
                float cc = y1[r] * rg;
                _Float16 h = (_Float16)cc;
                int idx = (quad * 4 + r) * 136 + ncol;
                sCCh[idx] = h;
                sCCl[idx] = (_Float16)(cc - (float)h);
            }
        }
        bar_lgkm();                                        // B4

        // ---- mm5: hn = tanh(cc @ Wn1 + bn1), K=128 (into sT alias) ----
        {
            half8 ah0 = *(const half8*)&sCCh[aOffH];
            half8 ah1 = *(const half8*)&sCCh[aOffH + 32];
            half8 ah2 = *(const half8*)&sCCh[aOffH + 64];
            half8 ah3 = *(const half8*)&sCCh[aOffH + 96];
            half8 al0 = *(const half8*)&sCCl[aOffH];
            half8 al1 = *(const half8*)&sCCl[aOffH + 32];
            half8 al2 = *(const half8*)&sCCl[aOffH + 64];
            half8 al3 = *(const half8*)&sCCl[aOffH + 96];
            floatx4 cn = {bn1v, bn1v, bn1v, bn1v};
            floatx4 nhh = MFMA(ah3, wN1[3].h, MFMA(ah2, wN1[2].h,
                          MFMA(ah1, wN1[1].h, MFMA(ah0, wN1[0].h, cn))));
            floatx4 nhl = MFMA(ah3, wN1[3].l, MFMA(ah2, wN1[2].l,
                          MFMA(ah1, wN1[1].l, MFMA(ah0, wN1[0].l, z))));
            floatx4 nlh = MFMA(al3, wN1[3].h, MFMA(al2, wN1[2].h,
                          MFMA(al1, wN1[1].h, MFMA(al0, wN1[0].h, z))));
            floatx4 aN = nhh + (nhl + nlh);
#pragma unroll
            for (int r = 0; r < 4; ++r) {
                float t = tanhf_fast(aN[r]);
                _Float16 h = (_Float16)t;
                int idx = (quad * 4 + r) * 72 + ncol;
                sTh[idx] = h;
                sTl[idx] = (_Float16)(t - (float)h);
            }
        }
        bar_lgkm();                                        // B5

        // ---- mm6: ns = hn@Wn2 + bn2; blend; state update ----
        {
            half8 n0h = *(const half8*)&sTh[aOff];
            half8 n0l = *(const half8*)&sTl[aOff];
            half8 n1h = *(const half8*)&sTh[aOff + 32];
            half8 n1l = *(const half8*)&sTl[aOff + 32];
            floatx4 cn = {bn2v, bn2v, bn2v, bn2v};
            floatx4 acc = MFMA(n1h, wN2[1].h, MFMA(n0h, wN2[0].h, cn))
                        + (MFMA(n1h, wN2[1].l, MFMA(n0h, wN2[0].l, z))
                         + MFMA(n1l, wN2[1].h, MFMA(n0l, wN2[0].h, z)));
#pragma unroll
            for (int r = 0; r < 4; ++r) {
                float ns = acc[r];
                float ny = (1.0f - uG[r]) * ns + uG[r] * y1[r];
                unsigned ap = apV[r];                      // hoisted at B2
                float nY = ap ? ny : y1[r];                // select: NaN-safe
                pc[r] = nY;
                int rr = quad * 4 + r;
                _Float16 h = (_Float16)nY;
                sYh[rr * 72 + ncol] = h;
                sYl[rr * 72 + ncol] = (_Float16)(nY - (float)h);
            }
        }
        bar_lgkm();                                        // B6

        // ---- rotate prefetched feat ----
#pragma unroll
        for (int r4 = 0; r4 < 4; ++r4) {
            hasU[r4] = hasN[r4];
            fv[r4] = fN[r4];
            mv[r4] = mN[r4];
        }
    }

    // ---- epilogue ----
#pragma unroll
    for (int r = 0; r < 4; ++r) {
        int b = rowBase + quad * 4 + r;
        out[(size_t)b * 64 + ncol] = pc[r];
    }
    float* out1 = out + (size_t)4096 * 64;
    float* out2 = out1 + (size_t)4096 * 63;
#pragma unroll
    for (int r4 = 0; r4 < 4; ++r4) {
        int row = 4 * wv + r4;
        int b = rowBase + row;
        if (lane < 63) {
            int t0 = tsteps[b * 64 + lane];
            int t1 = tsteps[b * 64 + lane + 1];
            int iv = t0 < 126 ? t0 : 126;
            out1[(size_t)b * 63 + lane] = sVol[row * 132 + iv + 1];
            out2[(size_t)b * 63 + lane] = (float)(t1 - t0);
        }
    }
}

extern "C" void kernel_launch(void* const* d_in, const int* in_sizes, int n_in,
                              void* d_out, int out_size, void* d_ws, size_t ws_size,
                              hipStream_t stream) {
    const float* data   = (const float*)d_in[0];
    const int*   tsteps = (const int*)  d_in[1];
    const float* Wu1 = (const float*)d_in[2];  const float* bu1 = (const float*)d_in[3];
    const float* Wu2 = (const float*)d_in[4];  const float* bu2 = (const float*)d_in[5];
    const float* Wr1 = (const float*)d_in[6];  const float* br1 = (const float*)d_in[7];
    const float* Wr2 = (const float*)d_in[8];  const float* br2 = (const float*)d_in[9];
    const float* Wn1 = (const float*)d_in[10]; const float* bn1 = (const float*)d_in[11];
    const float* Wn2 = (const float*)d_in[12]; const float* bn2 = (const float*)d_in[13];
    const float* Wo1 = (const float*)d_in[14]; const float* bo1 = (const float*)d_in[15];
    const float* Wo2 = (const float*)d_in[16]; const float* bo2 = (const float*)d_in[17];
    const float* Wd  = (const float*)d_in[18]; const float* bd  = (const float*)d_in[19];
    float* out = (float*)d_out;

    lobrm_fused<<<dim3(256), dim3(256), 0, stream>>>(
        data, tsteps, Wu1, bu1, Wu2, bu2, Wr1, br1, Wr2, br2,
        Wn1, bn1, Wn2, bn2, Wo1, bo1, Wo2, bo2, Wd, bd, out);
}